// Round 1
// baseline (885.184 us; speedup 1.0000x reference)
//
#include <hip/hip_runtime.h>
#include <stdint.h>

// ============================================================================
// SubspaceRankHopLayer on MI355X (gfx950)
//
// Math restructuring (exact in infinite precision):
//   lap_sum  = L @ (sum_k w_k hops_k)                    -> ONE 8192^2x256 GEMM
//   grad_sum = sum_k w_k (hops_k Q_k) M_k^-1 Q_k^T
//            = Zstack[8192,320] @ Rstack[320,256]        (Z_k = hops_k @ Q_k)
//   QR(U) replaced by CholeskyQR (downstream quantities are invariant to the
//   choice of orthonormal basis of col(U)).
// Heavy GEMMs in bf16 MFMA (f32->bf16 cvt on the fly for L); error budget
// << harness threshold (lap term bf16 rel err ~0.5% -> ~0.005 post-LN).
// ============================================================================

typedef __attribute__((ext_vector_type(8))) short  s16x8;   // 8 bf16 (4 VGPR)
typedef __attribute__((ext_vector_type(4))) float  f32x4;

#define NNODE 8192
#define DIN   256
#define KHOP  5
#define SDM   64

// ---------------- ws layout (bytes) ----------------
static const size_t OFF_Q    = 0;                                   // Q f32 [5][256][64]
static const size_t OFF_QT   = OFF_Q   + (size_t)5*256*64*4;        // Qt bf16 [5][64][256]
static const size_t OFF_ZT   = OFF_QT  + (size_t)5*64*256*2;        // Zt bf16 [5][8192][64]
static const size_t OFF_GP   = OFF_ZT  + (size_t)5*8192*64*2;       // Gpart f32 [5][64][64][64]
static const size_t OFF_LM   = OFF_GP  + (size_t)5*64*4096*4;       // Lm f32 [5][64][64]
static const size_t OFF_RD   = OFF_LM  + (size_t)5*4096*4;          // rdiag f32 [5][64]
static const size_t OFF_RE   = OFF_RD  + (size_t)5*64*4;            // rank_eff [5] (pad 64)
static const size_t OFF_W    = OFF_RE  + 64;                        // w [5] (pad 64)
static const size_t OFF_T2   = OFF_W   + 64;                        // T2w bf16 [5][256][64]
static const size_t OFF_HWT  = OFF_T2  + (size_t)5*256*64*2;        // hwT bf16 [256][8192]
static const size_t OFF_WBF  = OFF_HWT + (size_t)256*8192*2;        // W_in bf16 [256][256]
static const size_t OFF_HP   = OFF_WBF + (size_t)256*256*2;         // Hprox bf16 [8192][256]
static const size_t OFF_PART = OFF_HP  + (size_t)8192*256*2;        // partial bf16 [9][8192][256]
static const size_t OFF_HPRE = OFF_PART;                            // Hpre f32 [8192][256] (alias, partials dead)
// total ~55 MB of d_ws

__device__ __forceinline__ unsigned short f2bf(float f){
  unsigned u = __builtin_bit_cast(unsigned, f);
  u += 0x7FFFu + ((u >> 16) & 1u);            // RNE
  return (unsigned short)(u >> 16);
}
__device__ __forceinline__ float bf2f(unsigned h){
  return __builtin_bit_cast(float, h << 16);
}
__device__ __forceinline__ void gl_lds16(const void* g, void* l){
  // async global->LDS, 16B/lane; LDS dest = wave-uniform base + lane*16
  __builtin_amdgcn_global_load_lds(
      (const __attribute__((address_space(1))) void*)g,
      (__attribute__((address_space(3))) void*)l, 16, 0, 0);
}
__device__ __forceinline__ f32x4 mfma16(s16x8 a, s16x8 b, f32x4 c){
  return __builtin_amdgcn_mfma_f32_16x16x32_bf16(a, b, c, 0, 0, 0);
}

// in-place Cholesky of 64x64 SPD in LDS (pitch 65); rd = 1/diag. 256 threads.
__device__ void chol64(float* A, float* rd, int tid){
  #pragma unroll 1
  for (int j = 0; j < 64; ++j){
    if (tid == 0){
      float d = sqrtf(fmaxf(A[j*65+j], 1e-20f));
      A[j*65+j] = d; rd[j] = 1.0f / d;
    }
    __syncthreads();
    float rinv = rd[j];
    for (int i = j+1+tid; i < 64; i += 256) A[i*65+j] *= rinv;
    __syncthreads();
    int rem = 63 - j;
    for (int e = tid; e < rem*rem; e += 256){
      int i = j+1 + e/rem;
      int l = j+1 + (e - (e/rem)*rem);
      if (l <= i) A[i*65+l] -= A[i*65+j] * A[l*65+j];
    }
    __syncthreads();
  }
}

// ---------------------------------------------------------------------------
// K1: CholeskyQR of U_k [256,64]: A=U^T U, chol, Q = U L^-T. 5 blocks.
// ---------------------------------------------------------------------------
__global__ __launch_bounds__(256) void k_cholqr(const float* __restrict__ U,
                                                float* __restrict__ Qf,
                                                unsigned short* __restrict__ Qt){
  int k = blockIdx.x, tid = threadIdx.x;
  __shared__ float Ul[256*65];
  __shared__ float A[64*65];
  __shared__ float rd[64];
  const float* Uk = U + (size_t)k*16384;
  for (int e = tid; e < 16384; e += 256) Ul[(e>>6)*65 + (e&63)] = Uk[e];
  __syncthreads();
  int ti = tid >> 4, tj = tid & 15;
  float s[16];
  #pragma unroll
  for (int i = 0; i < 16; ++i) s[i] = 0.0f;
  for (int n = 0; n < 256; ++n){
    float xa[4], xb[4];
    #pragma unroll
    for (int p = 0; p < 4; ++p){ xa[p] = Ul[n*65 + ti*4 + p]; xb[p] = Ul[n*65 + tj*4 + p]; }
    #pragma unroll
    for (int p = 0; p < 4; ++p)
      #pragma unroll
      for (int q = 0; q < 4; ++q) s[p*4+q] += xa[p]*xb[q];
  }
  #pragma unroll
  for (int p = 0; p < 4; ++p)
    #pragma unroll
    for (int q = 0; q < 4; ++q) A[(ti*4+p)*65 + tj*4+q] = s[p*4+q];
  __syncthreads();
  chol64(A, rd, tid);
  // per-thread row n=tid: forward substitution  L x = u_row  -> Q row
  float x[64];
  #pragma unroll
  for (int j = 0; j < 64; ++j) x[j] = Ul[tid*65 + j];
  #pragma unroll
  for (int j = 0; j < 64; ++j){
    float ss = x[j];
    #pragma unroll
    for (int i = 0; i < j; ++i) ss -= A[j*65+i] * x[i];
    x[j] = ss * rd[j];
  }
  float* qo = Qf + ((size_t)k*256 + tid)*64;
  #pragma unroll
  for (int j = 0; j < 64; ++j) qo[j] = x[j];
  #pragma unroll
  for (int j = 0; j < 64; ++j) Ul[tid*65 + j] = x[j];
  __syncthreads();
  // Qt[k][s][d] bf16 (B^T layout for the Z GEMM)
  for (int e = tid; e < 16384; e += 256){
    int sc = e >> 8, d = e & 255;
    Qt[(size_t)k*16384 + e] = f2bf(Ul[d*65 + sc]);
  }
}

// ---------------------------------------------------------------------------
// K2: Z_k = hops_k @ Q_k  [8192,64] bf16.  grid(64,5), BM=128 BN=64 BK=64.
// ---------------------------------------------------------------------------
__global__ __launch_bounds__(256,2) void k_zgemm(const float* __restrict__ hops,
                                                 const unsigned short* __restrict__ Qt,
                                                 unsigned short* __restrict__ Zt){
  __shared__ __align__(16) unsigned short Al[128][72];
  __shared__ __align__(16) unsigned short Bl[64][64];
  int tid = threadIdx.x, lane = tid & 63, wave = tid >> 6;
  int q = lane >> 4, r = lane & 15;
  int k = blockIdx.y, m0 = blockIdx.x * 128;
  f32x4 acc[2][4];
  #pragma unroll
  for (int a = 0; a < 2; ++a)
    #pragma unroll
    for (int b = 0; b < 4; ++b) acc[a][b] = (f32x4){0,0,0,0};
  int rr = tid >> 1, half = tid & 1;
  for (int it = 0; it < 4; ++it){
    __syncthreads();
    #pragma unroll
    for (int i = 0; i < 2; ++i){
      int o = i*4096 + wave*1024 + lane*16;
      int srow = o >> 7, kc = (o & 127) >> 1;
      gl_lds16(Qt + (size_t)k*16384 + srow*256 + it*64 + kc,
               (char*)&Bl[0][0] + i*4096 + wave*1024);
    }
    const float* ga = hops + ((size_t)k*NNODE + m0 + rr)*256 + it*64 + half*32;
    f32x4 v[8];
    #pragma unroll
    for (int i = 0; i < 8; ++i) v[i] = *(const f32x4*)(ga + i*4);
    #pragma unroll
    for (int i = 0; i < 4; ++i){
      s16x8 t;
      #pragma unroll
      for (int j = 0; j < 8; ++j){ int e = i*8+j; t[j] = (short)f2bf(v[e>>2][e&3]); }
      *(s16x8*)&Al[rr][half*32 + i*8] = t;
    }
    __syncthreads();
    #pragma unroll
    for (int h = 0; h < 2; ++h){
      int ko = h*32 + q*8;
      s16x8 b[4];
      #pragma unroll
      for (int ni = 0; ni < 4; ++ni) b[ni] = *(const s16x8*)&Bl[ni*16 + r][ko];
      #pragma unroll
      for (int mi = 0; mi < 2; ++mi){
        s16x8 a = *(const s16x8*)&Al[wave*32 + mi*16 + r][ko];
        #pragma unroll
        for (int ni = 0; ni < 4; ++ni) acc[mi][ni] = mfma16(a, b[ni], acc[mi][ni]);
      }
    }
  }
  #pragma unroll
  for (int mi = 0; mi < 2; ++mi)
    #pragma unroll
    for (int ni = 0; ni < 4; ++ni)
      #pragma unroll
      for (int ii = 0; ii < 4; ++ii){
        int m = m0 + wave*32 + mi*16 + q*4 + ii;
        int sc = ni*16 + r;
        Zt[((size_t)k*NNODE + m)*64 + sc] = f2bf(acc[mi][ni][ii]);
      }
}

// ---------------------------------------------------------------------------
// K3: per-chunk partial Gram G_k += Z_chunk^T Z_chunk. grid(5,64), 128 rows/blk.
// ---------------------------------------------------------------------------
__global__ __launch_bounds__(256) void k_gpart(const unsigned short* __restrict__ Zt,
                                               float* __restrict__ Gp){
  int k = blockIdx.x, c = blockIdx.y, tid = threadIdx.x;
  __shared__ __align__(16) unsigned short Zl[128][64];
  const char* gb = (const char*)Zt + ((size_t)k*NNODE + c*128)*128;
  #pragma unroll
  for (int i = 0; i < 4; ++i){
    int o = i*4096 + tid*16;
    *(uint4*)((char*)&Zl[0][0] + o) = *(const uint4*)(gb + o);
  }
  __syncthreads();
  int ti = tid >> 4, tj = tid & 15;
  float acc[16];
  #pragma unroll
  for (int i = 0; i < 16; ++i) acc[i] = 0.0f;
  for (int n = 0; n < 128; ++n){
    const unsigned short* row = &Zl[n][0];
    uint2 ua = *(const uint2*)(row + ti*4);
    uint2 ub = *(const uint2*)(row + tj*4);
    float xa[4] = { bf2f(ua.x & 0xffff), bf2f(ua.x >> 16), bf2f(ua.y & 0xffff), bf2f(ua.y >> 16) };
    float xb[4] = { bf2f(ub.x & 0xffff), bf2f(ub.x >> 16), bf2f(ub.y & 0xffff), bf2f(ub.y >> 16) };
    #pragma unroll
    for (int p = 0; p < 4; ++p)
      #pragma unroll
      for (int qn = 0; qn < 4; ++qn) acc[p*4+qn] += xa[p]*xb[qn];
  }
  float* o = Gp + ((size_t)k*64 + c)*4096;
  #pragma unroll
  for (int p = 0; p < 4; ++p)
    #pragma unroll
    for (int qn = 0; qn < 4; ++qn) o[(ti*4+p)*64 + tj*4+qn] = acc[p*4+qn];
}

// ---------------------------------------------------------------------------
// K4: reduce Gpart -> G; rank_eff; M = I + coeff*G; chol(M). 5 blocks.
// ---------------------------------------------------------------------------
__global__ __launch_bounds__(256) void k_gred(const float* __restrict__ Gp,
                                              float* __restrict__ LmO,
                                              float* __restrict__ rdO,
                                              float* __restrict__ reO){
  int k = blockIdx.x, tid = threadIdx.x;
  __shared__ float A[64*65];
  __shared__ float rd[64];
  __shared__ float red[256];
  int ti = tid >> 4, tj = tid & 15;
  float s[16];
  #pragma unroll
  for (int i = 0; i < 16; ++i) s[i] = 0.0f;
  for (int c = 0; c < 64; ++c){
    const float* g = Gp + ((size_t)k*64 + c)*4096 + (ti*4)*64 + tj*4;
    #pragma unroll
    for (int p = 0; p < 4; ++p)
      #pragma unroll
      for (int qn = 0; qn < 4; ++qn) s[p*4+qn] += g[p*64+qn];
  }
  const float sc    = 1.0f / (8192.0f + 1e-8f);
  const float coeff = 64.0f / (8192.0f*0.25f + 1e-8f);
  float trp = 0.0f, tr2p = 0.0f;
  #pragma unroll
  for (int p = 0; p < 4; ++p)
    #pragma unroll
    for (int qn = 0; qn < 4; ++qn){
      float gg = s[p*4+qn];
      float sg = gg * sc;
      tr2p += sg*sg;
      int row = ti*4+p, col = tj*4+qn;
      if (row == col) trp += sg;
      A[row*65 + col] = (row == col ? 1.0f : 0.0f) + coeff*gg;
    }
  red[tid] = trp; __syncthreads();
  for (int o = 128; o > 0; o >>= 1){ if (tid < o) red[tid] += red[tid+o]; __syncthreads(); }
  float tr = red[0]; __syncthreads();
  red[tid] = tr2p; __syncthreads();
  for (int o = 128; o > 0; o >>= 1){ if (tid < o) red[tid] += red[tid+o]; __syncthreads(); }
  float tr2 = red[0]; __syncthreads();
  if (tid == 0) reO[k] = tr*tr / (tr2 + 1e-8f);
  chol64(A, rd, tid);
  for (int e = tid; e < 4096; e += 256) LmO[(size_t)k*4096 + e] = A[(e>>6)*65 + (e&63)];
  if (tid < 64) rdO[k*64 + tid] = rd[tid];
}

// ---------------------------------------------------------------------------
// K5: tau, softmax over rank_effs -> w; write output tail. 1 block.
// ---------------------------------------------------------------------------
__global__ void k_soft(const float* __restrict__ re, const float* __restrict__ ltau,
                       float* __restrict__ wv, float* __restrict__ dtail){
  if (threadIdx.x == 0){
    float tau = expf(ltau[0]);
    tau = fminf(fmaxf(tau, 0.1f), 10.0f);
    float r[5], m = -1e30f;
    for (int i = 0; i < 5; ++i){ r[i] = re[i]; m = fmaxf(m, r[i]); }
    float e[5], sum = 0.0f;
    for (int i = 0; i < 5; ++i){ e[i] = expf((r[i]-m)/tau); sum += e[i]; }
    for (int i = 0; i < 5; ++i){
      float w = e[i]/sum;
      wv[i] = w; dtail[i] = r[i]; dtail[5+i] = w;
    }
  }
}

// ---------------------------------------------------------------------------
// K6: T2w[k][n][s] = ETA*w_k * (M^-1 Q^T)[s][n] via 2 triangular solves. 5 blks.
// ---------------------------------------------------------------------------
__global__ __launch_bounds__(256) void k_t2w(const float* __restrict__ Qf,
                                             const float* __restrict__ LmI,
                                             const float* __restrict__ rdI,
                                             const float* __restrict__ wv,
                                             unsigned short* __restrict__ T2w){
  int k = blockIdx.x, n = threadIdx.x;
  __shared__ float A[64*65];
  __shared__ float rd[64];
  for (int e = n; e < 4096; e += 256) A[(e>>6)*65 + (e&63)] = LmI[(size_t)k*4096 + e];
  if (n < 64) rd[n] = rdI[k*64 + n];
  __syncthreads();
  float x[64];
  const float* qrow = Qf + ((size_t)k*256 + n)*64;
  #pragma unroll
  for (int j = 0; j < 64; ++j) x[j] = qrow[j];
  #pragma unroll
  for (int j = 0; j < 64; ++j){                 // forward: L z = q
    float ss = x[j];
    #pragma unroll
    for (int i = 0; i < j; ++i) ss -= A[j*65+i] * x[i];
    x[j] = ss * rd[j];
  }
  #pragma unroll
  for (int j = 63; j >= 0; --j){                // backward: L^T y = z
    float ss = x[j];
    #pragma unroll
    for (int i = j+1; i < 64; ++i) ss -= A[i*65+j] * x[i];
    x[j] = ss * rd[j];
  }
  float scale = 0.5f * wv[k];                   // ETA * w_k
  unsigned short* o = T2w + ((size_t)k*256 + n)*64;
  #pragma unroll
  for (int j = 0; j < 64; j += 2){
    unsigned uu = (unsigned)f2bf(scale*x[j]) | ((unsigned)f2bf(scale*x[j+1]) << 16);
    *(unsigned*)((char*)o + j*2) = uu;
  }
}

// ---------------------------------------------------------------------------
// K7: hwT[d][m] = sum_k (-ETA*LAM_LAP*w_k) hops[k][m][d]  (bf16, transposed).
// ---------------------------------------------------------------------------
__global__ __launch_bounds__(256) void k_hwT(const float* __restrict__ hops,
                                             const float* __restrict__ wv,
                                             unsigned short* __restrict__ hwT){
  __shared__ float T[64*65];
  int n0 = blockIdx.x*64, d0 = blockIdx.y*64, tid = threadIdx.x;
  float wl[5];
  #pragma unroll
  for (int k = 0; k < 5; ++k) wl[k] = -0.15f * wv[k];   // -ETA*LAM_LAP*w_k
  for (int e = tid; e < 1024; e += 256){
    int row = e >> 4, c4 = (e & 15)*4;
    f32x4 acc = (f32x4){0,0,0,0};
    #pragma unroll
    for (int k = 0; k < 5; ++k){
      f32x4 v = *(const f32x4*)(hops + ((size_t)k*NNODE + n0 + row)*256 + d0 + c4);
      acc += v * wl[k];
    }
    T[row*65 + c4+0] = acc[0]; T[row*65 + c4+1] = acc[1];
    T[row*65 + c4+2] = acc[2]; T[row*65 + c4+3] = acc[3];
  }
  __syncthreads();
  for (int e = tid; e < 1024; e += 256){
    int dr = e >> 4, c4 = (e & 15)*4;
    unsigned short h0 = f2bf(T[(c4+0)*65 + dr]);
    unsigned short h1 = f2bf(T[(c4+1)*65 + dr]);
    unsigned short h2 = f2bf(T[(c4+2)*65 + dr]);
    unsigned short h3 = f2bf(T[(c4+3)*65 + dr]);
    uint2 u; u.x = (unsigned)h0 | ((unsigned)h1 << 16); u.y = (unsigned)h2 | ((unsigned)h3 << 16);
    *(uint2*)(hwT + (size_t)(d0+dr)*NNODE + n0 + c4) = u;
  }
}

// K8: W_in f32 -> bf16 (layout already B^T: [out][in])
__global__ void k_wbf(const float* __restrict__ W, unsigned short* __restrict__ Wbf){
  int e = (blockIdx.x*256 + threadIdx.x)*4;
  f32x4 v = *(const f32x4*)(W + e);
  uint2 u;
  u.x = (unsigned)f2bf(v[0]) | ((unsigned)f2bf(v[1]) << 16);
  u.y = (unsigned)f2bf(v[2]) | ((unsigned)f2bf(v[3]) << 16);
  *(uint2*)(Wbf + e) = u;
}

// ---------------------------------------------------------------------------
// K9: the big one. partial[y] = L[:, yk:yk+1024] @ hwT^T  (bf16 out).
// grid(64,8), BM=128 BN=256 BK=64, f32->bf16 cvt of L in registers.
// ---------------------------------------------------------------------------
__global__ __launch_bounds__(256,2) void k_biggemm(const float* __restrict__ Lmat,
                                                   const unsigned short* __restrict__ Bt,
                                                   unsigned short* __restrict__ part){
  __shared__ __align__(16) unsigned short Al[128][72];
  __shared__ __align__(16) unsigned short Bl[256][64];
  int tid = threadIdx.x, lane = tid & 63, wave = tid >> 6;
  int q = lane >> 4, r = lane & 15;
  int m0 = blockIdx.x * 128;
  size_t kbase = (size_t)blockIdx.y * 1024;
  f32x4 acc[8][4];
  #pragma unroll
  for (int a = 0; a < 8; ++a)
    #pragma unroll
    for (int b = 0; b < 4; ++b) acc[a][b] = (f32x4){0,0,0,0};
  int rr = tid >> 1, half = tid & 1;
  for (int it = 0; it < 16; ++it){
    size_t k0 = kbase + it*64;
    __syncthreads();
    #pragma unroll
    for (int i = 0; i < 8; ++i){                 // B tile 256x64 bf16 via async DMA
      int o = i*4096 + wave*1024 + lane*16;
      int d = o >> 7, kc = (o & 127) >> 1;
      gl_lds16(Bt + (size_t)d*NNODE + k0 + kc,
               (char*)&Bl[0][0] + i*4096 + wave*1024);
    }
    const float* ga = Lmat + (size_t)(m0+rr)*NNODE + k0 + half*32;  // A tile 128x64 f32
    f32x4 v[8];
    #pragma unroll
    for (int i = 0; i < 8; ++i) v[i] = *(const f32x4*)(ga + i*4);
    #pragma unroll
    for (int i = 0; i < 4; ++i){
      s16x8 t;
      #pragma unroll
      for (int j = 0; j < 8; ++j){ int e = i*8+j; t[j] = (short)f2bf(v[e>>2][e&3]); }
      *(s16x8*)&Al[rr][half*32 + i*8] = t;
    }
    __syncthreads();
    #pragma unroll
    for (int h = 0; h < 2; ++h){
      int ko = h*32 + q*8;
      s16x8 b[4];
      #pragma unroll
      for (int ni = 0; ni < 4; ++ni) b[ni] = *(const s16x8*)&Bl[wave*64 + ni*16 + r][ko];
      #pragma unroll
      for (int mi = 0; mi < 8; ++mi){
        s16x8 a = *(const s16x8*)&Al[mi*16 + r][ko];
        #pragma unroll
        for (int ni = 0; ni < 4; ++ni) acc[mi][ni] = mfma16(a, b[ni], acc[mi][ni]);
      }
    }
  }
  unsigned short* o = part + (size_t)blockIdx.y * 2097152;
  #pragma unroll
  for (int mi = 0; mi < 8; ++mi)
    #pragma unroll
    for (int ni = 0; ni < 4; ++ni)
      #pragma unroll
      for (int ii = 0; ii < 4; ++ii){
        int m = m0 + mi*16 + q*4 + ii;
        int n = wave*64 + ni*16 + r;
        o[(size_t)m*256 + n] = f2bf(acc[mi][ni][ii]);
      }
}

// ---------------------------------------------------------------------------
// K10: grad partial = Zstack[8192,320] @ T2w-stack[320,256] -> slab 8.
// grid(256), BM=32 BN=256, K=320 (5 hops x 64).
// ---------------------------------------------------------------------------
__global__ __launch_bounds__(256,2) void k_gradgemm(const unsigned short* __restrict__ Zt,
                                                    const unsigned short* __restrict__ T2w,
                                                    unsigned short* __restrict__ out){
  __shared__ __align__(16) unsigned short Al[32][64];
  __shared__ __align__(16) unsigned short Bl[256][64];
  int tid = threadIdx.x, lane = tid & 63, wave = tid >> 6;
  int q = lane >> 4, r = lane & 15;
  int m0 = blockIdx.x * 32;
  f32x4 acc[2][4];
  #pragma unroll
  for (int a = 0; a < 2; ++a)
    #pragma unroll
    for (int b = 0; b < 4; ++b) acc[a][b] = (f32x4){0,0,0,0};
  for (int kk = 0; kk < 5; ++kk){
    __syncthreads();
    {
      int o = wave*1024 + lane*16;   // A: 4KB contiguous (Zt rows are 128B)
      gl_lds16((const char*)Zt + ((size_t)kk*NNODE + m0)*128 + o,
               (char*)&Al[0][0] + wave*1024);
      (void)o;
    }
    #pragma unroll
    for (int i = 0; i < 8; ++i){   // B: 32KB contiguous (T2w hop block)
      int o = i*4096 + wave*1024 + lane*16;
      gl_lds16((const char*)T2w + (size_t)kk*32768 + o,
               (char*)&Bl[0][0] + i*4096 + wave*1024);
    }
    __syncthreads();
    #pragma unroll
    for (int h = 0; h < 2; ++h){
      int ko = h*32 + q*8;
      s16x8 b[4];
      #pragma unroll
      for (int ni = 0; ni < 4; ++ni) b[ni] = *(const s16x8*)&Bl[wave*64 + ni*16 + r][ko];
      #pragma unroll
      for (int mi = 0; mi < 2; ++mi){
        s16x8 a = *(const s16x8*)&Al[mi*16 + r][ko];
        #pragma unroll
        for (int ni = 0; ni < 4; ++ni) acc[mi][ni] = mfma16(a, b[ni], acc[mi][ni]);
      }
    }
  }
  #pragma unroll
  for (int mi = 0; mi < 2; ++mi)
    #pragma unroll
    for (int ni = 0; ni < 4; ++ni)
      #pragma unroll
      for (int ii = 0; ii < 4; ++ii){
        int m = m0 + mi*16 + q*4 + ii;
        int n = wave*64 + ni*16 + r;
        out[(size_t)m*256 + n] = f2bf(acc[mi][ni][ii]);
      }
}

// K11: H_half = H + sum(9 partial slabs); soft-threshold; -> Hprox bf16
__global__ __launch_bounds__(256) void k_combine(const float* __restrict__ H,
                                                 const unsigned short* __restrict__ part,
                                                 unsigned short* __restrict__ Hp){
  size_t e = ((size_t)blockIdx.x*256 + threadIdx.x)*4;
  f32x4 h = *(const f32x4*)(H + e);
  float s0 = h[0], s1 = h[1], s2 = h[2], s3 = h[3];
  #pragma unroll
  for (int sl = 0; sl < 9; ++sl){
    uint2 u = *(const uint2*)(part + (size_t)sl*2097152 + e);
    s0 += bf2f(u.x & 0xffff); s1 += bf2f(u.x >> 16);
    s2 += bf2f(u.y & 0xffff); s3 += bf2f(u.y >> 16);
  }
  #define PROX(a) ({ float _t = fabsf(a) - 0.025f; _t > 0.0f ? copysignf(_t,(a)) : 0.0f; })
  uint2 o;
  o.x = (unsigned)f2bf(PROX(s0)) | ((unsigned)f2bf(PROX(s1)) << 16);
  o.y = (unsigned)f2bf(PROX(s2)) | ((unsigned)f2bf(PROX(s3)) << 16);
  *(uint2*)(Hp + e) = o;
}

// K12: Hpre = Hprox @ W_in^T (bf16 MFMA). grid(128), BM=64 BN=256 K=256.
__global__ __launch_bounds__(256,2) void k_fingemm(const unsigned short* __restrict__ Hp,
                                                   const unsigned short* __restrict__ Wbf,
                                                   float* __restrict__ Hpre){
  __shared__ __align__(16) unsigned short Al[64][64];
  __shared__ __align__(16) unsigned short Bl[256][64];
  int tid = threadIdx.x, lane = tid & 63, wave = tid >> 6;
  int q = lane >> 4, r = lane & 15;
  int m0 = blockIdx.x * 64;
  f32x4 acc[4][4];
  #pragma unroll
  for (int a = 0; a < 4; ++a)
    #pragma unroll
    for (int b = 0; b < 4; ++b) acc[a][b] = (f32x4){0,0,0,0};
  for (int it = 0; it < 4; ++it){
    __syncthreads();
    #pragma unroll
    for (int i = 0; i < 2; ++i){
      int o = i*4096 + wave*1024 + lane*16;
      int row = o >> 7, kc = o & 127;
      gl_lds16((const char*)Hp + (size_t)(m0+row)*512 + it*128 + kc,
               (char*)&Al[0][0] + i*4096 + wave*1024);
    }
    #pragma unroll
    for (int i = 0; i < 8; ++i){
      int o = i*4096 + wave*1024 + lane*16;
      int n = o >> 7, kc = o & 127;
      gl_lds16((const char*)Wbf + (size_t)n*512 + it*128 + kc,
               (char*)&Bl[0][0] + i*4096 + wave*1024);
    }
    __syncthreads();
    #pragma unroll
    for (int h = 0; h < 2; ++h){
      int ko = h*32 + q*8;
      s16x8 b[4];
      #pragma unroll
      for (int ni = 0; ni < 4; ++ni) b[ni] = *(const s16x8*)&Bl[wave*64 + ni*16 + r][ko];
      #pragma unroll
      for (int mi = 0; mi < 4; ++mi){
        s16x8 a = *(const s16x8*)&Al[mi*16 + r][ko];
        #pragma unroll
        for (int ni = 0; ni < 4; ++ni) acc[mi][ni] = mfma16(a, b[ni], acc[mi][ni]);
      }
    }
  }
  #pragma unroll
  for (int mi = 0; mi < 4; ++mi)
    #pragma unroll
    for (int ni = 0; ni < 4; ++ni)
      #pragma unroll
      for (int ii = 0; ii < 4; ++ii){
        int m = m0 + mi*16 + q*4 + ii;
        int n = wave*64 + ni*16 + r;
        Hpre[(size_t)m*256 + n] = acc[mi][ni][ii];
      }
}

// K13: LayerNorm per row (256). 1 wave per row, 4 rows/block.
__global__ __launch_bounds__(256) void k_ln(const float* __restrict__ Hpre,
                                            const float* __restrict__ gamma,
                                            const float* __restrict__ beta,
                                            float* __restrict__ out){
  int row = blockIdx.x*4 + (threadIdx.x >> 6);
  int lane = threadIdx.x & 63;
  f32x4 x = *(const f32x4*)(Hpre + (size_t)row*256 + lane*4);
  float sm = x[0]+x[1]+x[2]+x[3];
  float sq = x[0]*x[0]+x[1]*x[1]+x[2]*x[2]+x[3]*x[3];
  #pragma unroll
  for (int o = 1; o < 64; o <<= 1){ sm += __shfl_xor(sm, o, 64); sq += __shfl_xor(sq, o, 64); }
  float mean = sm * (1.0f/256.0f);
  float var  = sq * (1.0f/256.0f) - mean*mean;
  float rs   = rsqrtf(var + 1e-5f);
  f32x4 g = *(const f32x4*)(gamma + lane*4);
  f32x4 b = *(const f32x4*)(beta  + lane*4);
  f32x4 y;
  #pragma unroll
  for (int i = 0; i < 4; ++i) y[i] = (x[i]-mean)*rs*g[i] + b[i];
  *(f32x4*)(out + (size_t)row*256 + lane*4) = y;
}

// ===========================================================================
extern "C" void kernel_launch(void* const* d_in, const int* in_sizes, int n_in,
                              void* d_out, int out_size, void* d_ws, size_t ws_size,
                              hipStream_t stream){
  const float* H    = (const float*)d_in[0];
  const float* hops = (const float*)d_in[1];
  const float* Lmat = (const float*)d_in[2];
  const float* U    = (const float*)d_in[3];
  const float* Win  = (const float*)d_in[4];
  const float* gam  = (const float*)d_in[5];
  const float* bet  = (const float*)d_in[6];
  const float* ltau = (const float*)d_in[7];
  float* out = (float*)d_out;

  char* ws = (char*)d_ws;
  float*          Qf   = (float*)(ws + OFF_Q);
  unsigned short* Qt   = (unsigned short*)(ws + OFF_QT);
  unsigned short* Zt   = (unsigned short*)(ws + OFF_ZT);
  float*          Gp   = (float*)(ws + OFF_GP);
  float*          Lm   = (float*)(ws + OFF_LM);
  float*          rdw  = (float*)(ws + OFF_RD);
  float*          re   = (float*)(ws + OFF_RE);
  float*          wv   = (float*)(ws + OFF_W);
  unsigned short* T2w  = (unsigned short*)(ws + OFF_T2);
  unsigned short* hwT  = (unsigned short*)(ws + OFF_HWT);
  unsigned short* Wbf  = (unsigned short*)(ws + OFF_WBF);
  unsigned short* Hp   = (unsigned short*)(ws + OFF_HP);
  unsigned short* part = (unsigned short*)(ws + OFF_PART);
  float*          Hpre = (float*)(ws + OFF_HPRE);

  hipLaunchKernelGGL(k_cholqr,  dim3(5),        dim3(256), 0, stream, U, Qf, Qt);
  hipLaunchKernelGGL(k_zgemm,   dim3(64,5),     dim3(256), 0, stream, hops, Qt, Zt);
  hipLaunchKernelGGL(k_gpart,   dim3(5,64),     dim3(256), 0, stream, Zt, Gp);
  hipLaunchKernelGGL(k_gred,    dim3(5),        dim3(256), 0, stream, Gp, Lm, rdw, re);
  hipLaunchKernelGGL(k_soft,    dim3(1),        dim3(64),  0, stream, re, ltau, wv, out + 2097152);
  hipLaunchKernelGGL(k_t2w,     dim3(5),        dim3(256), 0, stream, Qf, Lm, rdw, wv, T2w);
  hipLaunchKernelGGL(k_hwT,     dim3(128,4),    dim3(256), 0, stream, hops, wv, hwT);
  hipLaunchKernelGGL(k_wbf,     dim3(64),       dim3(256), 0, stream, Win, Wbf);
  hipLaunchKernelGGL(k_biggemm, dim3(64,8),     dim3(256), 0, stream, Lmat, hwT, part);
  hipLaunchKernelGGL(k_gradgemm,dim3(256),      dim3(256), 0, stream, Zt, T2w, part + (size_t)8*2097152);
  hipLaunchKernelGGL(k_combine, dim3(2048),     dim3(256), 0, stream, H, part, Hp);
  hipLaunchKernelGGL(k_fingemm, dim3(128),      dim3(256), 0, stream, Hp, Wbf, Hpre);
  hipLaunchKernelGGL(k_ln,      dim3(2048),     dim3(256), 0, stream, Hpre, gam, bet, out);
}

// Round 2
// 732.647 us; speedup vs baseline: 1.2082x; 1.2082x over previous
//
#include <hip/hip_runtime.h>
#include <stdint.h>

// ============================================================================
// SubspaceRankHopLayer on MI355X (gfx950)
//
// R2: replace per-thread unrolled triangular solves (256-VGPR spill monsters,
// 5-block grids, 170us each) with wave-parallel solves: lane i holds x[i],
// pivot broadcast via __shfl, predicated FMA update. Split k_cholqr into
// gram+chol (5 blocks) and wave-parallel Q-solve (320 blocks). Shrink Gram
// partial chunks 64 -> 16 so k_gred reads 4x less.
// ============================================================================

typedef __attribute__((ext_vector_type(8))) short  s16x8;   // 8 bf16 (4 VGPR)
typedef __attribute__((ext_vector_type(4))) float  f32x4;

#define NNODE 8192
#define DIN   256
#define KHOP  5
#define SDM   64

// ---------------- ws layout (bytes) ----------------
static const size_t OFF_Q    = 0;                                   // Q f32 [5][256][64]
static const size_t OFF_QT   = OFF_Q   + (size_t)5*256*64*4;        // Qt bf16 [5][64][256]
static const size_t OFF_ZT   = OFF_QT  + (size_t)5*64*256*2;        // Zt bf16 [5][8192][64]
static const size_t OFF_GP   = OFF_ZT  + (size_t)5*8192*64*2;       // Gpart f32 [5][16][64][64]
static const size_t OFF_LM   = OFF_GP  + (size_t)5*16*4096*4;       // Lm f32 [5][64][64]
static const size_t OFF_RD   = OFF_LM  + (size_t)5*4096*4;          // rdiag f32 [5][64]
static const size_t OFF_LU   = OFF_RD  + (size_t)5*64*4;            // Lu f32 [5][64][64]
static const size_t OFF_RDU  = OFF_LU  + (size_t)5*4096*4;          // rdiag_u f32 [5][64]
static const size_t OFF_RE   = OFF_RDU + (size_t)5*64*4;            // rank_eff [5] (pad 64)
static const size_t OFF_W    = OFF_RE  + 64;                        // w [5] (pad 64)
static const size_t OFF_T2   = OFF_W   + 64;                        // T2w bf16 [5][256][64]
static const size_t OFF_HWT  = OFF_T2  + (size_t)5*256*64*2;        // hwT bf16 [256][8192]
static const size_t OFF_WBF  = OFF_HWT + (size_t)256*8192*2;        // W_in bf16 [256][256]
static const size_t OFF_HP   = OFF_WBF + (size_t)256*256*2;         // Hprox bf16 [8192][256]
static const size_t OFF_PART = OFF_HP  + (size_t)8192*256*2;        // partial bf16 [9][8192][256]
static const size_t OFF_HPRE = OFF_PART;                            // Hpre f32 [8192][256] (alias)

__device__ __forceinline__ unsigned short f2bf(float f){
  unsigned u = __builtin_bit_cast(unsigned, f);
  u += 0x7FFFu + ((u >> 16) & 1u);            // RNE
  return (unsigned short)(u >> 16);
}
__device__ __forceinline__ float bf2f(unsigned h){
  return __builtin_bit_cast(float, h << 16);
}
__device__ __forceinline__ void gl_lds16(const void* g, void* l){
  __builtin_amdgcn_global_load_lds(
      (const __attribute__((address_space(1))) void*)g,
      (__attribute__((address_space(3))) void*)l, 16, 0, 0);
}
__device__ __forceinline__ f32x4 mfma16(s16x8 a, s16x8 b, f32x4 c){
  return __builtin_amdgcn_mfma_f32_16x16x32_bf16(a, b, c, 0, 0, 0);
}

// in-place Cholesky of 64x64 SPD in LDS (pitch 65); rd = 1/diag. 256 threads.
__device__ void chol64(float* A, float* rd, int tid){
  #pragma unroll 1
  for (int j = 0; j < 64; ++j){
    if (tid == 0){
      float d = sqrtf(fmaxf(A[j*65+j], 1e-20f));
      A[j*65+j] = d; rd[j] = 1.0f / d;
    }
    __syncthreads();
    float rinv = rd[j];
    for (int i = j+1+tid; i < 64; i += 256) A[i*65+j] *= rinv;
    __syncthreads();
    int rem = 63 - j;
    for (int e = tid; e < rem*rem; e += 256){
      int i = j+1 + e/rem;
      int l = j+1 + (e - (e/rem)*rem);
      if (l <= i) A[i*65+l] -= A[i*65+j] * A[l*65+j];
    }
    __syncthreads();
  }
}

// ---------------------------------------------------------------------------
// K1a: Gram + Cholesky of U_k [256,64]: A=U^T U, chol. 5 blocks.
// ---------------------------------------------------------------------------
__global__ __launch_bounds__(256) void k_gramchol(const float* __restrict__ U,
                                                  float* __restrict__ Lu,
                                                  float* __restrict__ rdu){
  int k = blockIdx.x, tid = threadIdx.x;
  __shared__ float Ul[256*65];
  __shared__ float A[64*65];
  __shared__ float rd[64];
  const float* Uk = U + (size_t)k*16384;
  for (int e = tid; e < 16384; e += 256) Ul[(e>>6)*65 + (e&63)] = Uk[e];
  __syncthreads();
  int ti = tid >> 4, tj = tid & 15;
  float s[16];
  #pragma unroll
  for (int i = 0; i < 16; ++i) s[i] = 0.0f;
  for (int n = 0; n < 256; ++n){
    float xa[4], xb[4];
    #pragma unroll
    for (int p = 0; p < 4; ++p){ xa[p] = Ul[n*65 + ti*4 + p]; xb[p] = Ul[n*65 + tj*4 + p]; }
    #pragma unroll
    for (int p = 0; p < 4; ++p)
      #pragma unroll
      for (int q = 0; q < 4; ++q) s[p*4+q] += xa[p]*xb[q];
  }
  #pragma unroll
  for (int p = 0; p < 4; ++p)
    #pragma unroll
    for (int q = 0; q < 4; ++q) A[(ti*4+p)*65 + tj*4+q] = s[p*4+q];
  __syncthreads();
  chol64(A, rd, tid);
  for (int e = tid; e < 4096; e += 256) Lu[(size_t)k*4096 + e] = A[(e>>6)*65 + (e&63)];
  if (tid < 64) rdu[k*64 + tid] = rd[tid];
}

// ---------------------------------------------------------------------------
// K1b: wave-parallel forward solve L x = u_row -> Q rows. grid(64,5), 4 waves.
// Lane i owns x[i]; pivot broadcast via shfl; LDS column read is 2-way (free).
// ---------------------------------------------------------------------------
__global__ __launch_bounds__(256) void k_qsolve(const float* __restrict__ U,
                                                const float* __restrict__ Lu,
                                                const float* __restrict__ rdu,
                                                float* __restrict__ Qf,
                                                unsigned short* __restrict__ Qt){
  int k = blockIdx.y, tid = threadIdx.x, wave = tid >> 6, lane = tid & 63;
  __shared__ float Al[64*65];
  __shared__ float rds[64];
  for (int e = tid; e < 4096; e += 256) Al[(e>>6)*65 + (e&63)] = Lu[(size_t)k*4096 + e];
  if (tid < 64) rds[tid] = rdu[k*64 + tid];
  __syncthreads();
  int n = blockIdx.x*4 + wave;
  float x = U[((size_t)k*256 + n)*64 + lane];
  #pragma unroll
  for (int j = 0; j < 64; ++j){
    float zj = __shfl(x, j) * rds[j];
    x = (lane == j) ? zj : (lane > j ? x - Al[lane*65+j]*zj : x);
  }
  Qf[((size_t)k*256 + n)*64 + lane] = x;
  Qt[(size_t)k*16384 + lane*256 + n] = f2bf(x);   // Qt[k][s][d]
}

// ---------------------------------------------------------------------------
// K2: Z_k = hops_k @ Q_k  [8192,64] bf16.  grid(64,5), BM=128 BN=64 BK=64.
// ---------------------------------------------------------------------------
__global__ __launch_bounds__(256,2) void k_zgemm(const float* __restrict__ hops,
                                                 const unsigned short* __restrict__ Qt,
                                                 unsigned short* __restrict__ Zt){
  __shared__ __align__(16) unsigned short Al[128][72];
  __shared__ __align__(16) unsigned short Bl[64][64];
  int tid = threadIdx.x, lane = tid & 63, wave = tid >> 6;
  int q = lane >> 4, r = lane & 15;
  int k = blockIdx.y, m0 = blockIdx.x * 128;
  f32x4 acc[2][4];
  #pragma unroll
  for (int a = 0; a < 2; ++a)
    #pragma unroll
    for (int b = 0; b < 4; ++b) acc[a][b] = (f32x4){0,0,0,0};
  int rr = tid >> 1, half = tid & 1;
  for (int it = 0; it < 4; ++it){
    __syncthreads();
    #pragma unroll
    for (int i = 0; i < 2; ++i){
      int o = i*4096 + wave*1024 + lane*16;
      int srow = o >> 7, kc = (o & 127) >> 1;
      gl_lds16(Qt + (size_t)k*16384 + srow*256 + it*64 + kc,
               (char*)&Bl[0][0] + i*4096 + wave*1024);
    }
    const float* ga = hops + ((size_t)k*NNODE + m0 + rr)*256 + it*64 + half*32;
    f32x4 v[8];
    #pragma unroll
    for (int i = 0; i < 8; ++i) v[i] = *(const f32x4*)(ga + i*4);
    #pragma unroll
    for (int i = 0; i < 4; ++i){
      s16x8 t;
      #pragma unroll
      for (int j = 0; j < 8; ++j){ int e = i*8+j; t[j] = (short)f2bf(v[e>>2][e&3]); }
      *(s16x8*)&Al[rr][half*32 + i*8] = t;
    }
    __syncthreads();
    #pragma unroll
    for (int h = 0; h < 2; ++h){
      int ko = h*32 + q*8;
      s16x8 b[4];
      #pragma unroll
      for (int ni = 0; ni < 4; ++ni) b[ni] = *(const s16x8*)&Bl[ni*16 + r][ko];
      #pragma unroll
      for (int mi = 0; mi < 2; ++mi){
        s16x8 a = *(const s16x8*)&Al[wave*32 + mi*16 + r][ko];
        #pragma unroll
        for (int ni = 0; ni < 4; ++ni) acc[mi][ni] = mfma16(a, b[ni], acc[mi][ni]);
      }
    }
  }
  #pragma unroll
  for (int mi = 0; mi < 2; ++mi)
    #pragma unroll
    for (int ni = 0; ni < 4; ++ni)
      #pragma unroll
      for (int ii = 0; ii < 4; ++ii){
        int m = m0 + wave*32 + mi*16 + q*4 + ii;
        int sc = ni*16 + r;
        Zt[((size_t)k*NNODE + m)*64 + sc] = f2bf(acc[mi][ni][ii]);
      }
}

// ---------------------------------------------------------------------------
// K3: partial Gram over 512-row chunks. grid(5,16).
// ---------------------------------------------------------------------------
__global__ __launch_bounds__(256) void k_gpart(const unsigned short* __restrict__ Zt,
                                               float* __restrict__ Gp){
  int k = blockIdx.x, c = blockIdx.y, tid = threadIdx.x;
  __shared__ __align__(16) unsigned short Zl[128][64];
  int ti = tid >> 4, tj = tid & 15;
  float acc[16];
  #pragma unroll
  for (int i = 0; i < 16; ++i) acc[i] = 0.0f;
  for (int sub = 0; sub < 4; ++sub){
    const char* gb = (const char*)Zt + ((size_t)k*NNODE + c*512 + sub*128)*128;
    __syncthreads();
    #pragma unroll
    for (int i = 0; i < 4; ++i){
      int o = i*4096 + tid*16;
      *(uint4*)((char*)&Zl[0][0] + o) = *(const uint4*)(gb + o);
    }
    __syncthreads();
    for (int n = 0; n < 128; ++n){
      const unsigned short* row = &Zl[n][0];
      uint2 ua = *(const uint2*)(row + ti*4);
      uint2 ub = *(const uint2*)(row + tj*4);
      float xa[4] = { bf2f(ua.x & 0xffff), bf2f(ua.x >> 16), bf2f(ua.y & 0xffff), bf2f(ua.y >> 16) };
      float xb[4] = { bf2f(ub.x & 0xffff), bf2f(ub.x >> 16), bf2f(ub.y & 0xffff), bf2f(ub.y >> 16) };
      #pragma unroll
      for (int p = 0; p < 4; ++p)
        #pragma unroll
        for (int qn = 0; qn < 4; ++qn) acc[p*4+qn] += xa[p]*xb[qn];
    }
  }
  float* o = Gp + ((size_t)k*16 + c)*4096;
  #pragma unroll
  for (int p = 0; p < 4; ++p)
    #pragma unroll
    for (int qn = 0; qn < 4; ++qn) o[(ti*4+p)*64 + tj*4+qn] = acc[p*4+qn];
}

// ---------------------------------------------------------------------------
// K4: reduce Gpart -> G; rank_eff; M = I + coeff*G; chol(M). 5 blocks.
// ---------------------------------------------------------------------------
__global__ __launch_bounds__(256) void k_gred(const float* __restrict__ Gp,
                                              float* __restrict__ LmO,
                                              float* __restrict__ rdO,
                                              float* __restrict__ reO){
  int k = blockIdx.x, tid = threadIdx.x;
  __shared__ float A[64*65];
  __shared__ float rd[64];
  __shared__ float red[256];
  int ti = tid >> 4, tj = tid & 15;
  float s[16];
  #pragma unroll
  for (int i = 0; i < 16; ++i) s[i] = 0.0f;
  for (int c = 0; c < 16; ++c){
    const float* g = Gp + ((size_t)k*16 + c)*4096 + (ti*4)*64 + tj*4;
    #pragma unroll
    for (int p = 0; p < 4; ++p)
      #pragma unroll
      for (int qn = 0; qn < 4; ++qn) s[p*4+qn] += g[p*64+qn];
  }
  const float sc    = 1.0f / (8192.0f + 1e-8f);
  const float coeff = 64.0f / (8192.0f*0.25f + 1e-8f);
  float trp = 0.0f, tr2p = 0.0f;
  #pragma unroll
  for (int p = 0; p < 4; ++p)
    #pragma unroll
    for (int qn = 0; qn < 4; ++qn){
      float gg = s[p*4+qn];
      float sg = gg * sc;
      tr2p += sg*sg;
      int row = ti*4+p, col = tj*4+qn;
      if (row == col) trp += sg;
      A[row*65 + col] = (row == col ? 1.0f : 0.0f) + coeff*gg;
    }
  red[tid] = trp; __syncthreads();
  for (int o = 128; o > 0; o >>= 1){ if (tid < o) red[tid] += red[tid+o]; __syncthreads(); }
  float tr = red[0]; __syncthreads();
  red[tid] = tr2p; __syncthreads();
  for (int o = 128; o > 0; o >>= 1){ if (tid < o) red[tid] += red[tid+o]; __syncthreads(); }
  float tr2 = red[0]; __syncthreads();
  if (tid == 0) reO[k] = tr*tr / (tr2 + 1e-8f);
  chol64(A, rd, tid);
  for (int e = tid; e < 4096; e += 256) LmO[(size_t)k*4096 + e] = A[(e>>6)*65 + (e&63)];
  if (tid < 64) rdO[k*64 + tid] = rd[tid];
}

// ---------------------------------------------------------------------------
// K5: tau, softmax over rank_effs -> w; write output tail. 1 block.
// ---------------------------------------------------------------------------
__global__ void k_soft(const float* __restrict__ re, const float* __restrict__ ltau,
                       float* __restrict__ wv, float* __restrict__ dtail){
  if (threadIdx.x == 0){
    float tau = expf(ltau[0]);
    tau = fminf(fmaxf(tau, 0.1f), 10.0f);
    float r[5], m = -1e30f;
    for (int i = 0; i < 5; ++i){ r[i] = re[i]; m = fmaxf(m, r[i]); }
    float e[5], sum = 0.0f;
    for (int i = 0; i < 5; ++i){ e[i] = expf((r[i]-m)/tau); sum += e[i]; }
    for (int i = 0; i < 5; ++i){
      float w = e[i]/sum;
      wv[i] = w; dtail[i] = r[i]; dtail[5+i] = w;
    }
  }
}

// ---------------------------------------------------------------------------
// K6: wave-parallel fwd+bwd solve: T2w[k][n][s] = ETA*w_k*(M^-1 Q^T)[s][n].
// grid(64,5), 4 waves/block, lane i owns x[i].
// ---------------------------------------------------------------------------
__global__ __launch_bounds__(256) void k_t2w(const float* __restrict__ Qf,
                                             const float* __restrict__ LmI,
                                             const float* __restrict__ rdI,
                                             const float* __restrict__ wv,
                                             unsigned short* __restrict__ T2w){
  int k = blockIdx.y, tid = threadIdx.x, wave = tid >> 6, lane = tid & 63;
  __shared__ float Al[64*65];
  __shared__ float rds[64];
  for (int e = tid; e < 4096; e += 256) Al[(e>>6)*65 + (e&63)] = LmI[(size_t)k*4096 + e];
  if (tid < 64) rds[tid] = rdI[k*64 + tid];
  __syncthreads();
  int n = blockIdx.x*4 + wave;
  float x = Qf[((size_t)k*256 + n)*64 + lane];
  #pragma unroll
  for (int j = 0; j < 64; ++j){                 // forward: L z = q
    float zj = __shfl(x, j) * rds[j];
    x = (lane == j) ? zj : (lane > j ? x - Al[lane*65+j]*zj : x);
  }
  #pragma unroll
  for (int j = 63; j >= 0; --j){                // backward: L^T y = z
    float yj = __shfl(x, j) * rds[j];
    x = (lane == j) ? yj : (lane < j ? x - Al[j*65+lane]*yj : x);
  }
  float scale = 0.5f * wv[k];                   // ETA * w_k
  T2w[((size_t)k*256 + n)*64 + lane] = f2bf(scale * x);
}

// ---------------------------------------------------------------------------
// K7: hwT[d][m] = sum_k (-ETA*LAM_LAP*w_k) hops[k][m][d]  (bf16, transposed).
// ---------------------------------------------------------------------------
__global__ __launch_bounds__(256) void k_hwT(const float* __restrict__ hops,
                                             const float* __restrict__ wv,
                                             unsigned short* __restrict__ hwT){
  __shared__ float T[64*65];
  int n0 = blockIdx.x*64, d0 = blockIdx.y*64, tid = threadIdx.x;
  float wl[5];
  #pragma unroll
  for (int k = 0; k < 5; ++k) wl[k] = -0.15f * wv[k];   // -ETA*LAM_LAP*w_k
  for (int e = tid; e < 1024; e += 256){
    int row = e >> 4, c4 = (e & 15)*4;
    f32x4 acc = (f32x4){0,0,0,0};
    #pragma unroll
    for (int k = 0; k < 5; ++k){
      f32x4 v = *(const f32x4*)(hops + ((size_t)k*NNODE + n0 + row)*256 + d0 + c4);
      acc += v * wl[k];
    }
    T[row*65 + c4+0] = acc[0]; T[row*65 + c4+1] = acc[1];
    T[row*65 + c4+2] = acc[2]; T[row*65 + c4+3] = acc[3];
  }
  __syncthreads();
  for (int e = tid; e < 1024; e += 256){
    int dr = e >> 4, c4 = (e & 15)*4;
    unsigned short h0 = f2bf(T[(c4+0)*65 + dr]);
    unsigned short h1 = f2bf(T[(c4+1)*65 + dr]);
    unsigned short h2 = f2bf(T[(c4+2)*65 + dr]);
    unsigned short h3 = f2bf(T[(c4+3)*65 + dr]);
    uint2 u; u.x = (unsigned)h0 | ((unsigned)h1 << 16); u.y = (unsigned)h2 | ((unsigned)h3 << 16);
    *(uint2*)(hwT + (size_t)(d0+dr)*NNODE + n0 + c4) = u;
  }
}

// K8: W_in f32 -> bf16 (layout already B^T: [out][in])
__global__ void k_wbf(const float* __restrict__ W, unsigned short* __restrict__ Wbf){
  int e = (blockIdx.x*256 + threadIdx.x)*4;
  f32x4 v = *(const f32x4*)(W + e);
  uint2 u;
  u.x = (unsigned)f2bf(v[0]) | ((unsigned)f2bf(v[1]) << 16);
  u.y = (unsigned)f2bf(v[2]) | ((unsigned)f2bf(v[3]) << 16);
  *(uint2*)(Wbf + e) = u;
}

// ---------------------------------------------------------------------------
// K9: partial[y] = L[:, yk:yk+1024] @ hwT^T  (bf16 out). grid(64,8).
// ---------------------------------------------------------------------------
__global__ __launch_bounds__(256,2) void k_biggemm(const float* __restrict__ Lmat,
                                                   const unsigned short* __restrict__ Bt,
                                                   unsigned short* __restrict__ part){
  __shared__ __align__(16) unsigned short Al[128][72];
  __shared__ __align__(16) unsigned short Bl[256][64];
  int tid = threadIdx.x, lane = tid & 63, wave = tid >> 6;
  int q = lane >> 4, r = lane & 15;
  int m0 = blockIdx.x * 128;
  size_t kbase = (size_t)blockIdx.y * 1024;
  f32x4 acc[8][4];
  #pragma unroll
  for (int a = 0; a < 8; ++a)
    #pragma unroll
    for (int b = 0; b < 4; ++b) acc[a][b] = (f32x4){0,0,0,0};
  int rr = tid >> 1, half = tid & 1;
  for (int it = 0; it < 16; ++it){
    size_t k0 = kbase + it*64;
    __syncthreads();
    #pragma unroll
    for (int i = 0; i < 8; ++i){
      int o = i*4096 + wave*1024 + lane*16;
      int d = o >> 7, kc = (o & 127) >> 1;
      gl_lds16(Bt + (size_t)d*NNODE + k0 + kc,
               (char*)&Bl[0][0] + i*4096 + wave*1024);
    }
    const float* ga = Lmat + (size_t)(m0+rr)*NNODE + k0 + half*32;
    f32x4 v[8];
    #pragma unroll
    for (int i = 0; i < 8; ++i) v[i] = *(const f32x4*)(ga + i*4);
    #pragma unroll
    for (int i = 0; i < 4; ++i){
      s16x8 t;
      #pragma unroll
      for (int j = 0; j < 8; ++j){ int e = i*8+j; t[j] = (short)f2bf(v[e>>2][e&3]); }
      *(s16x8*)&Al[rr][half*32 + i*8] = t;
    }
    __syncthreads();
    #pragma unroll
    for (int h = 0; h < 2; ++h){
      int ko = h*32 + q*8;
      s16x8 b[4];
      #pragma unroll
      for (int ni = 0; ni < 4; ++ni) b[ni] = *(const s16x8*)&Bl[wave*64 + ni*16 + r][ko];
      #pragma unroll
      for (int mi = 0; mi < 8; ++mi){
        s16x8 a = *(const s16x8*)&Al[mi*16 + r][ko];
        #pragma unroll
        for (int ni = 0; ni < 4; ++ni) acc[mi][ni] = mfma16(a, b[ni], acc[mi][ni]);
      }
    }
  }
  unsigned short* o = part + (size_t)blockIdx.y * 2097152;
  #pragma unroll
  for (int mi = 0; mi < 8; ++mi)
    #pragma unroll
    for (int ni = 0; ni < 4; ++ni)
      #pragma unroll
      for (int ii = 0; ii < 4; ++ii){
        int m = m0 + mi*16 + q*4 + ii;
        int n = wave*64 + ni*16 + r;
        o[(size_t)m*256 + n] = f2bf(acc[mi][ni][ii]);
      }
}

// ---------------------------------------------------------------------------
// K10: grad partial = Zstack[8192,320] @ T2w-stack[320,256] -> slab 8.
// ---------------------------------------------------------------------------
__global__ __launch_bounds__(256,2) void k_gradgemm(const unsigned short* __restrict__ Zt,
                                                    const unsigned short* __restrict__ T2w,
                                                    unsigned short* __restrict__ out){
  __shared__ __align__(16) unsigned short Al[32][64];
  __shared__ __align__(16) unsigned short Bl[256][64];
  int tid = threadIdx.x, lane = tid & 63, wave = tid >> 6;
  int q = lane >> 4, r = lane & 15;
  int m0 = blockIdx.x * 32;
  f32x4 acc[2][4];
  #pragma unroll
  for (int a = 0; a < 2; ++a)
    #pragma unroll
    for (int b = 0; b < 4; ++b) acc[a][b] = (f32x4){0,0,0,0};
  for (int kk = 0; kk < 5; ++kk){
    __syncthreads();
    {
      int o = wave*1024 + lane*16;
      gl_lds16((const char*)Zt + ((size_t)kk*NNODE + m0)*128 + o,
               (char*)&Al[0][0] + wave*1024);
    }
    #pragma unroll
    for (int i = 0; i < 8; ++i){
      int o = i*4096 + wave*1024 + lane*16;
      gl_lds16((const char*)T2w + (size_t)kk*32768 + o,
               (char*)&Bl[0][0] + i*4096 + wave*1024);
    }
    __syncthreads();
    #pragma unroll
    for (int h = 0; h < 2; ++h){
      int ko = h*32 + q*8;
      s16x8 b[4];
      #pragma unroll
      for (int ni = 0; ni < 4; ++ni) b[ni] = *(const s16x8*)&Bl[wave*64 + ni*16 + r][ko];
      #pragma unroll
      for (int mi = 0; mi < 2; ++mi){
        s16x8 a = *(const s16x8*)&Al[mi*16 + r][ko];
        #pragma unroll
        for (int ni = 0; ni < 4; ++ni) acc[mi][ni] = mfma16(a, b[ni], acc[mi][ni]);
      }
    }
  }
  #pragma unroll
  for (int mi = 0; mi < 2; ++mi)
    #pragma unroll
    for (int ni = 0; ni < 4; ++ni)
      #pragma unroll
      for (int ii = 0; ii < 4; ++ii){
        int m = m0 + mi*16 + q*4 + ii;
        int n = wave*64 + ni*16 + r;
        out[(size_t)m*256 + n] = f2bf(acc[mi][ni][ii]);
      }
}

// K11: H_half = H + sum(9 partial slabs); soft-threshold; -> Hprox bf16
__global__ __launch_bounds__(256) void k_combine(const float* __restrict__ H,
                                                 const unsigned short* __restrict__ part,
                                                 unsigned short* __restrict__ Hp){
  size_t e = ((size_t)blockIdx.x*256 + threadIdx.x)*4;
  f32x4 h = *(const f32x4*)(H + e);
  float s0 = h[0], s1 = h[1], s2 = h[2], s3 = h[3];
  #pragma unroll
  for (int sl = 0; sl < 9; ++sl){
    uint2 u = *(const uint2*)(part + (size_t)sl*2097152 + e);
    s0 += bf2f(u.x & 0xffff); s1 += bf2f(u.x >> 16);
    s2 += bf2f(u.y & 0xffff); s3 += bf2f(u.y >> 16);
  }
  #define PROX(a) ({ float _t = fabsf(a) - 0.025f; _t > 0.0f ? copysignf(_t,(a)) : 0.0f; })
  uint2 o;
  o.x = (unsigned)f2bf(PROX(s0)) | ((unsigned)f2bf(PROX(s1)) << 16);
  o.y = (unsigned)f2bf(PROX(s2)) | ((unsigned)f2bf(PROX(s3)) << 16);
  *(uint2*)(Hp + e) = o;
}

// K12: Hpre = Hprox @ W_in^T (bf16 MFMA). grid(128), BM=64 BN=256 K=256.
__global__ __launch_bounds__(256,2) void k_fingemm(const unsigned short* __restrict__ Hp,
                                                   const unsigned short* __restrict__ Wbf,
                                                   float* __restrict__ Hpre){
  __shared__ __align__(16) unsigned short Al[64][64];
  __shared__ __align__(16) unsigned short Bl[256][64];
  int tid = threadIdx.x, lane = tid & 63, wave = tid >> 6;
  int q = lane >> 4, r = lane & 15;
  int m0 = blockIdx.x * 64;
  f32x4 acc[4][4];
  #pragma unroll
  for (int a = 0; a < 4; ++a)
    #pragma unroll
    for (int b = 0; b < 4; ++b) acc[a][b] = (f32x4){0,0,0,0};
  for (int it = 0; it < 4; ++it){
    __syncthreads();
    #pragma unroll
    for (int i = 0; i < 2; ++i){
      int o = i*4096 + wave*1024 + lane*16;
      int row = o >> 7, kc = o & 127;
      gl_lds16((const char*)Hp + (size_t)(m0+row)*512 + it*128 + kc,
               (char*)&Al[0][0] + i*4096 + wave*1024);
    }
    #pragma unroll
    for (int i = 0; i < 8; ++i){
      int o = i*4096 + wave*1024 + lane*16;
      int n = o >> 7, kc = o & 127;
      gl_lds16((const char*)Wbf + (size_t)n*512 + it*128 + kc,
               (char*)&Bl[0][0] + i*4096 + wave*1024);
    }
    __syncthreads();
    #pragma unroll
    for (int h = 0; h < 2; ++h){
      int ko = h*32 + q*8;
      s16x8 b[4];
      #pragma unroll
      for (int ni = 0; ni < 4; ++ni) b[ni] = *(const s16x8*)&Bl[wave*64 + ni*16 + r][ko];
      #pragma unroll
      for (int mi = 0; mi < 4; ++mi){
        s16x8 a = *(const s16x8*)&Al[mi*16 + r][ko];
        #pragma unroll
        for (int ni = 0; ni < 4; ++ni) acc[mi][ni] = mfma16(a, b[ni], acc[mi][ni]);
      }
    }
  }
  #pragma unroll
  for (int mi = 0; mi < 4; ++mi)
    #pragma unroll
    for (int ni = 0; ni < 4; ++ni)
      #pragma unroll
      for (int ii = 0; ii < 4; ++ii){
        int m = m0 + mi*16 + q*4 + ii;
        int n = wave*64 + ni*16 + r;
        Hpre[(size_t)m*256 + n] = acc[mi][ni][ii];
      }
}

// K13: LayerNorm per row (256). 1 wave per row, 4 rows/block.
__global__ __launch_bounds__(256) void k_ln(const float* __restrict__ Hpre,
                                            const float* __restrict__ gamma,
                                            const float* __restrict__ beta,
                                            float* __restrict__ out){
  int row = blockIdx.x*4 + (threadIdx.x >> 6);
  int lane = threadIdx.x & 63;
  f32x4 x = *(const f32x4*)(Hpre + (size_t)row*256 + lane*4);
  float sm = x[0]+x[1]+x[2]+x[3];
  float sq = x[0]*x[0]+x[1]*x[1]+x[2]*x[2]+x[3]*x[3];
  #pragma unroll
  for (int o = 1; o < 64; o <<= 1){ sm += __shfl_xor(sm, o, 64); sq += __shfl_xor(sq, o, 64); }
  float mean = sm * (1.0f/256.0f);
  float var  = sq * (1.0f/256.0f) - mean*mean;
  float rs   = rsqrtf(var + 1e-5f);
  f32x4 g = *(const f32x4*)(gamma + lane*4);
  f32x4 b = *(const f32x4*)(beta  + lane*4);
  f32x4 y;
  #pragma unroll
  for (int i = 0; i < 4; ++i) y[i] = (x[i]-mean)*rs*g[i] + b[i];
  *(f32x4*)(out + (size_t)row*256 + lane*4) = y;
}

// ===========================================================================
extern "C" void kernel_launch(void* const* d_in, const int* in_sizes, int n_in,
                              void* d_out, int out_size, void* d_ws, size_t ws_size,
                              hipStream_t stream){
  const float* H    = (const float*)d_in[0];
  const float* hops = (const float*)d_in[1];
  const float* Lmat = (const float*)d_in[2];
  const float* U    = (const float*)d_in[3];
  const float* Win  = (const float*)d_in[4];
  const float* gam  = (const float*)d_in[5];
  const float* bet  = (const float*)d_in[6];
  const float* ltau = (const float*)d_in[7];
  float* out = (float*)d_out;

  char* ws = (char*)d_ws;
  float*          Qf   = (float*)(ws + OFF_Q);
  unsigned short* Qt   = (unsigned short*)(ws + OFF_QT);
  unsigned short* Zt   = (unsigned short*)(ws + OFF_ZT);
  float*          Gp   = (float*)(ws + OFF_GP);
  float*          Lm   = (float*)(ws + OFF_LM);
  float*          rdw  = (float*)(ws + OFF_RD);
  float*          Lu   = (float*)(ws + OFF_LU);
  float*          rdu  = (float*)(ws + OFF_RDU);
  float*          re   = (float*)(ws + OFF_RE);
  float*          wv   = (float*)(ws + OFF_W);
  unsigned short* T2w  = (unsigned short*)(ws + OFF_T2);
  unsigned short* hwT  = (unsigned short*)(ws + OFF_HWT);
  unsigned short* Wbf  = (unsigned short*)(ws + OFF_WBF);
  unsigned short* Hp   = (unsigned short*)(ws + OFF_HP);
  unsigned short* part = (unsigned short*)(ws + OFF_PART);
  float*          Hpre = (float*)(ws + OFF_HPRE);

  hipLaunchKernelGGL(k_gramchol,dim3(5),        dim3(256), 0, stream, U, Lu, rdu);
  hipLaunchKernelGGL(k_qsolve,  dim3(64,5),     dim3(256), 0, stream, U, Lu, rdu, Qf, Qt);
  hipLaunchKernelGGL(k_zgemm,   dim3(64,5),     dim3(256), 0, stream, hops, Qt, Zt);
  hipLaunchKernelGGL(k_gpart,   dim3(5,16),     dim3(256), 0, stream, Zt, Gp);
  hipLaunchKernelGGL(k_gred,    dim3(5),        dim3(256), 0, stream, Gp, Lm, rdw, re);
  hipLaunchKernelGGL(k_soft,    dim3(1),        dim3(64),  0, stream, re, ltau, wv, out + 2097152);
  hipLaunchKernelGGL(k_t2w,     dim3(64,5),     dim3(256), 0, stream, Qf, Lm, rdw, wv, T2w);
  hipLaunchKernelGGL(k_hwT,     dim3(128,4),    dim3(256), 0, stream, hops, wv, hwT);
  hipLaunchKernelGGL(k_wbf,     dim3(64),       dim3(256), 0, stream, Win, Wbf);
  hipLaunchKernelGGL(k_biggemm, dim3(64,8),     dim3(256), 0, stream, Lmat, hwT, part);
  hipLaunchKernelGGL(k_gradgemm,dim3(256),      dim3(256), 0, stream, Zt, T2w, part + (size_t)8*2097152);
  hipLaunchKernelGGL(k_combine, dim3(2048),     dim3(256), 0, stream, H, part, Hp);
  hipLaunchKernelGGL(k_fingemm, dim3(128),      dim3(256), 0, stream, Hp, Wbf, Hpre);
  hipLaunchKernelGGL(k_ln,      dim3(2048),     dim3(256), 0, stream, Hpre, gam, bet, out);
}

// Round 3
// 728.907 us; speedup vs baseline: 1.2144x; 1.0051x over previous
//
#include <hip/hip_runtime.h>
#include <stdint.h>

// ============================================================================
// SubspaceRankHopLayer on MI355X (gfx950)
//
// R3: k_biggemm was latency-bound (MfmaUtil 8%, HBM 1.15 TB/s, 5.2M LDS
// conflicts): per-iter in-wave vmcnt(0) stall on scattered f32 L loads +
// 128B-pitch LDS causing quad-wide bank collisions. Fix: prepass L->bf16
// (k_lbf, streaming), then m97-style pure-DMA GEMM (global_load_lds for both
// operands) with chunk-padded LDS (1 KB DMA chunks at 1040 B stride ->
// balanced 8-lane/bank-quad ds_read_b128).
// ============================================================================

typedef __attribute__((ext_vector_type(8))) short  s16x8;   // 8 bf16 (4 VGPR)
typedef __attribute__((ext_vector_type(4))) float  f32x4;

#define NNODE 8192
#define DIN   256
#define KHOP  5
#define SDM   64

// ---------------- ws layout (bytes) ----------------
static const size_t OFF_Q    = 0;                                   // Q f32 [5][256][64]
static const size_t OFF_QT   = OFF_Q   + (size_t)5*256*64*4;        // Qt bf16 [5][64][256]
static const size_t OFF_ZT   = OFF_QT  + (size_t)5*64*256*2;        // Zt bf16 [5][8192][64]
static const size_t OFF_GP   = OFF_ZT  + (size_t)5*8192*64*2;       // Gpart f32 [5][16][64][64]
static const size_t OFF_LM   = OFF_GP  + (size_t)5*16*4096*4;       // Lm f32 [5][64][64]
static const size_t OFF_RD   = OFF_LM  + (size_t)5*4096*4;          // rdiag f32 [5][64]
static const size_t OFF_LU   = OFF_RD  + (size_t)5*64*4;            // Lu f32 [5][64][64]
static const size_t OFF_RDU  = OFF_LU  + (size_t)5*4096*4;          // rdiag_u f32 [5][64]
static const size_t OFF_RE   = OFF_RDU + (size_t)5*64*4;            // rank_eff [5] (pad 64)
static const size_t OFF_W    = OFF_RE  + 64;                        // w [5] (pad 64)
static const size_t OFF_T2   = OFF_W   + 64;                        // T2w bf16 [5][256][64]
static const size_t OFF_HWT  = OFF_T2  + (size_t)5*256*64*2;        // hwT bf16 [256][8192]
static const size_t OFF_WBF  = OFF_HWT + (size_t)256*8192*2;        // W_in bf16 [256][256]
static const size_t OFF_HP   = OFF_WBF + (size_t)256*256*2;         // Hprox bf16 [8192][256]
static const size_t OFF_PART = OFF_HP  + (size_t)8192*256*2;        // partial bf16 [9][8192][256]
static const size_t OFF_HPRE = OFF_PART;                            // Hpre f32 [8192][256] (alias)
static const size_t OFF_LBF  = OFF_PART + (size_t)9*8192*256*2;     // L bf16 [8192][8192] (128 MB)

__device__ __forceinline__ unsigned short f2bf(float f){
  unsigned u = __builtin_bit_cast(unsigned, f);
  u += 0x7FFFu + ((u >> 16) & 1u);            // RNE
  return (unsigned short)(u >> 16);
}
__device__ __forceinline__ float bf2f(unsigned h){
  return __builtin_bit_cast(float, h << 16);
}
__device__ __forceinline__ void gl_lds16(const void* g, void* l){
  __builtin_amdgcn_global_load_lds(
      (const __attribute__((address_space(1))) void*)g,
      (__attribute__((address_space(3))) void*)l, 16, 0, 0);
}
__device__ __forceinline__ f32x4 mfma16(s16x8 a, s16x8 b, f32x4 c){
  return __builtin_amdgcn_mfma_f32_16x16x32_bf16(a, b, c, 0, 0, 0);
}

// in-place Cholesky of 64x64 SPD in LDS (pitch 65); rd = 1/diag. 256 threads.
__device__ void chol64(float* A, float* rd, int tid){
  #pragma unroll 1
  for (int j = 0; j < 64; ++j){
    if (tid == 0){
      float d = sqrtf(fmaxf(A[j*65+j], 1e-20f));
      A[j*65+j] = d; rd[j] = 1.0f / d;
    }
    __syncthreads();
    float rinv = rd[j];
    for (int i = j+1+tid; i < 64; i += 256) A[i*65+j] *= rinv;
    __syncthreads();
    int rem = 63 - j;
    for (int e = tid; e < rem*rem; e += 256){
      int i = j+1 + e/rem;
      int l = j+1 + (e - (e/rem)*rem);
      if (l <= i) A[i*65+l] -= A[i*65+j] * A[l*65+j];
    }
    __syncthreads();
  }
}

// ---------------------------------------------------------------------------
// K0: L f32 -> bf16 streaming cvt. grid 32768.
// ---------------------------------------------------------------------------
__global__ __launch_bounds__(256) void k_lbf(const float* __restrict__ L,
                                             unsigned short* __restrict__ Lbf){
  size_t e = ((size_t)blockIdx.x*256 + threadIdx.x)*8;
  f32x4 a = *(const f32x4*)(L + e);
  f32x4 b = *(const f32x4*)(L + e + 4);
  uint4 u;
  u.x = (unsigned)f2bf(a[0]) | ((unsigned)f2bf(a[1]) << 16);
  u.y = (unsigned)f2bf(a[2]) | ((unsigned)f2bf(a[3]) << 16);
  u.z = (unsigned)f2bf(b[0]) | ((unsigned)f2bf(b[1]) << 16);
  u.w = (unsigned)f2bf(b[2]) | ((unsigned)f2bf(b[3]) << 16);
  *(uint4*)(Lbf + e) = u;
}

// ---------------------------------------------------------------------------
// K1a: Gram + Cholesky of U_k [256,64]: A=U^T U, chol. 5 blocks.
// ---------------------------------------------------------------------------
__global__ __launch_bounds__(256) void k_gramchol(const float* __restrict__ U,
                                                  float* __restrict__ Lu,
                                                  float* __restrict__ rdu){
  int k = blockIdx.x, tid = threadIdx.x;
  __shared__ float Ul[256*65];
  __shared__ float A[64*65];
  __shared__ float rd[64];
  const float* Uk = U + (size_t)k*16384;
  for (int e = tid; e < 16384; e += 256) Ul[(e>>6)*65 + (e&63)] = Uk[e];
  __syncthreads();
  int ti = tid >> 4, tj = tid & 15;
  float s[16];
  #pragma unroll
  for (int i = 0; i < 16; ++i) s[i] = 0.0f;
  for (int n = 0; n < 256; ++n){
    float xa[4], xb[4];
    #pragma unroll
    for (int p = 0; p < 4; ++p){ xa[p] = Ul[n*65 + ti*4 + p]; xb[p] = Ul[n*65 + tj*4 + p]; }
    #pragma unroll
    for (int p = 0; p < 4; ++p)
      #pragma unroll
      for (int q = 0; q < 4; ++q) s[p*4+q] += xa[p]*xb[q];
  }
  #pragma unroll
  for (int p = 0; p < 4; ++p)
    #pragma unroll
    for (int q = 0; q < 4; ++q) A[(ti*4+p)*65 + tj*4+q] = s[p*4+q];
  __syncthreads();
  chol64(A, rd, tid);
  for (int e = tid; e < 4096; e += 256) Lu[(size_t)k*4096 + e] = A[(e>>6)*65 + (e&63)];
  if (tid < 64) rdu[k*64 + tid] = rd[tid];
}

// ---------------------------------------------------------------------------
// K1b: wave-parallel forward solve L x = u_row -> Q rows. grid(64,5).
// ---------------------------------------------------------------------------
__global__ __launch_bounds__(256) void k_qsolve(const float* __restrict__ U,
                                                const float* __restrict__ Lu,
                                                const float* __restrict__ rdu,
                                                float* __restrict__ Qf,
                                                unsigned short* __restrict__ Qt){
  int k = blockIdx.y, tid = threadIdx.x, wave = tid >> 6, lane = tid & 63;
  __shared__ float Al[64*65];
  __shared__ float rds[64];
  for (int e = tid; e < 4096; e += 256) Al[(e>>6)*65 + (e&63)] = Lu[(size_t)k*4096 + e];
  if (tid < 64) rds[tid] = rdu[k*64 + tid];
  __syncthreads();
  int n = blockIdx.x*4 + wave;
  float x = U[((size_t)k*256 + n)*64 + lane];
  #pragma unroll
  for (int j = 0; j < 64; ++j){
    float zj = __shfl(x, j) * rds[j];
    x = (lane == j) ? zj : (lane > j ? x - Al[lane*65+j]*zj : x);
  }
  Qf[((size_t)k*256 + n)*64 + lane] = x;
  Qt[(size_t)k*16384 + lane*256 + n] = f2bf(x);   // Qt[k][s][d]
}

// ---------------------------------------------------------------------------
// K2: Z_k = hops_k @ Q_k  [8192,64] bf16.  grid(64,5), BM=128 BN=64 BK=64.
// ---------------------------------------------------------------------------
__global__ __launch_bounds__(256,2) void k_zgemm(const float* __restrict__ hops,
                                                 const unsigned short* __restrict__ Qt,
                                                 unsigned short* __restrict__ Zt){
  __shared__ __align__(16) unsigned short Al[128][72];
  __shared__ __align__(16) unsigned short Bl[64][64];
  int tid = threadIdx.x, lane = tid & 63, wave = tid >> 6;
  int q = lane >> 4, r = lane & 15;
  int k = blockIdx.y, m0 = blockIdx.x * 128;
  f32x4 acc[2][4];
  #pragma unroll
  for (int a = 0; a < 2; ++a)
    #pragma unroll
    for (int b = 0; b < 4; ++b) acc[a][b] = (f32x4){0,0,0,0};
  int rr = tid >> 1, half = tid & 1;
  for (int it = 0; it < 4; ++it){
    __syncthreads();
    #pragma unroll
    for (int i = 0; i < 2; ++i){
      int o = i*4096 + wave*1024 + lane*16;
      int srow = o >> 7, kc = (o & 127) >> 1;
      gl_lds16(Qt + (size_t)k*16384 + srow*256 + it*64 + kc,
               (char*)&Bl[0][0] + i*4096 + wave*1024);
    }
    const float* ga = hops + ((size_t)k*NNODE + m0 + rr)*256 + it*64 + half*32;
    f32x4 v[8];
    #pragma unroll
    for (int i = 0; i < 8; ++i) v[i] = *(const f32x4*)(ga + i*4);
    #pragma unroll
    for (int i = 0; i < 4; ++i){
      s16x8 t;
      #pragma unroll
      for (int j = 0; j < 8; ++j){ int e = i*8+j; t[j] = (short)f2bf(v[e>>2][e&3]); }
      *(s16x8*)&Al[rr][half*32 + i*8] = t;
    }
    __syncthreads();
    #pragma unroll
    for (int h = 0; h < 2; ++h){
      int ko = h*32 + q*8;
      s16x8 b[4];
      #pragma unroll
      for (int ni = 0; ni < 4; ++ni) b[ni] = *(const s16x8*)&Bl[ni*16 + r][ko];
      #pragma unroll
      for (int mi = 0; mi < 2; ++mi){
        s16x8 a = *(const s16x8*)&Al[wave*32 + mi*16 + r][ko];
        #pragma unroll
        for (int ni = 0; ni < 4; ++ni) acc[mi][ni] = mfma16(a, b[ni], acc[mi][ni]);
      }
    }
  }
  #pragma unroll
  for (int mi = 0; mi < 2; ++mi)
    #pragma unroll
    for (int ni = 0; ni < 4; ++ni)
      #pragma unroll
      for (int ii = 0; ii < 4; ++ii){
        int m = m0 + wave*32 + mi*16 + q*4 + ii;
        int sc = ni*16 + r;
        Zt[((size_t)k*NNODE + m)*64 + sc] = f2bf(acc[mi][ni][ii]);
      }
}

// ---------------------------------------------------------------------------
// K3: partial Gram over 512-row chunks. grid(5,16).
// ---------------------------------------------------------------------------
__global__ __launch_bounds__(256) void k_gpart(const unsigned short* __restrict__ Zt,
                                               float* __restrict__ Gp){
  int k = blockIdx.x, c = blockIdx.y, tid = threadIdx.x;
  __shared__ __align__(16) unsigned short Zl[128][64];
  int ti = tid >> 4, tj = tid & 15;
  float acc[16];
  #pragma unroll
  for (int i = 0; i < 16; ++i) acc[i] = 0.0f;
  for (int sub = 0; sub < 4; ++sub){
    const char* gb = (const char*)Zt + ((size_t)k*NNODE + c*512 + sub*128)*128;
    __syncthreads();
    #pragma unroll
    for (int i = 0; i < 4; ++i){
      int o = i*4096 + tid*16;
      *(uint4*)((char*)&Zl[0][0] + o) = *(const uint4*)(gb + o);
    }
    __syncthreads();
    for (int n = 0; n < 128; ++n){
      const unsigned short* row = &Zl[n][0];
      uint2 ua = *(const uint2*)(row + ti*4);
      uint2 ub = *(const uint2*)(row + tj*4);
      float xa[4] = { bf2f(ua.x & 0xffff), bf2f(ua.x >> 16), bf2f(ua.y & 0xffff), bf2f(ua.y >> 16) };
      float xb[4] = { bf2f(ub.x & 0xffff), bf2f(ub.x >> 16), bf2f(ub.y & 0xffff), bf2f(ub.y >> 16) };
      #pragma unroll
      for (int p = 0; p < 4; ++p)
        #pragma unroll
        for (int qn = 0; qn < 4; ++qn) acc[p*4+qn] += xa[p]*xb[qn];
    }
  }
  float* o = Gp + ((size_t)k*16 + c)*4096;
  #pragma unroll
  for (int p = 0; p < 4; ++p)
    #pragma unroll
    for (int qn = 0; qn < 4; ++qn) o[(ti*4+p)*64 + tj*4+qn] = acc[p*4+qn];
}

// ---------------------------------------------------------------------------
// K4: reduce Gpart -> G; rank_eff; M = I + coeff*G; chol(M). 5 blocks.
// ---------------------------------------------------------------------------
__global__ __launch_bounds__(256) void k_gred(const float* __restrict__ Gp,
                                              float* __restrict__ LmO,
                                              float* __restrict__ rdO,
                                              float* __restrict__ reO){
  int k = blockIdx.x, tid = threadIdx.x;
  __shared__ float A[64*65];
  __shared__ float rd[64];
  __shared__ float red[256];
  int ti = tid >> 4, tj = tid & 15;
  float s[16];
  #pragma unroll
  for (int i = 0; i < 16; ++i) s[i] = 0.0f;
  for (int c = 0; c < 16; ++c){
    const float* g = Gp + ((size_t)k*16 + c)*4096 + (ti*4)*64 + tj*4;
    #pragma unroll
    for (int p = 0; p < 4; ++p)
      #pragma unroll
      for (int qn = 0; qn < 4; ++qn) s[p*4+qn] += g[p*64+qn];
  }
  const float sc    = 1.0f / (8192.0f + 1e-8f);
  const float coeff = 64.0f / (8192.0f*0.25f + 1e-8f);
  float trp = 0.0f, tr2p = 0.0f;
  #pragma unroll
  for (int p = 0; p < 4; ++p)
    #pragma unroll
    for (int qn = 0; qn < 4; ++qn){
      float gg = s[p*4+qn];
      float sg = gg * sc;
      tr2p += sg*sg;
      int row = ti*4+p, col = tj*4+qn;
      if (row == col) trp += sg;
      A[row*65 + col] = (row == col ? 1.0f : 0.0f) + coeff*gg;
    }
  red[tid] = trp; __syncthreads();
  for (int o = 128; o > 0; o >>= 1){ if (tid < o) red[tid] += red[tid+o]; __syncthreads(); }
  float tr = red[0]; __syncthreads();
  red[tid] = tr2p; __syncthreads();
  for (int o = 128; o > 0; o >>= 1){ if (tid < o) red[tid] += red[tid+o]; __syncthreads(); }
  float tr2 = red[0]; __syncthreads();
  if (tid == 0) reO[k] = tr*tr / (tr2 + 1e-8f);
  chol64(A, rd, tid);
  for (int e = tid; e < 4096; e += 256) LmO[(size_t)k*4096 + e] = A[(e>>6)*65 + (e&63)];
  if (tid < 64) rdO[k*64 + tid] = rd[tid];
}

// ---------------------------------------------------------------------------
// K5: tau, softmax over rank_effs -> w; write output tail. 1 block.
// ---------------------------------------------------------------------------
__global__ void k_soft(const float* __restrict__ re, const float* __restrict__ ltau,
                       float* __restrict__ wv, float* __restrict__ dtail){
  if (threadIdx.x == 0){
    float tau = expf(ltau[0]);
    tau = fminf(fmaxf(tau, 0.1f), 10.0f);
    float r[5], m = -1e30f;
    for (int i = 0; i < 5; ++i){ r[i] = re[i]; m = fmaxf(m, r[i]); }
    float e[5], sum = 0.0f;
    for (int i = 0; i < 5; ++i){ e[i] = expf((r[i]-m)/tau); sum += e[i]; }
    for (int i = 0; i < 5; ++i){
      float w = e[i]/sum;
      wv[i] = w; dtail[i] = r[i]; dtail[5+i] = w;
    }
  }
}

// ---------------------------------------------------------------------------
// K6: wave-parallel fwd+bwd solve: T2w[k][n][s] = ETA*w_k*(M^-1 Q^T)[s][n].
// ---------------------------------------------------------------------------
__global__ __launch_bounds__(256) void k_t2w(const float* __restrict__ Qf,
                                             const float* __restrict__ LmI,
                                             const float* __restrict__ rdI,
                                             const float* __restrict__ wv,
                                             unsigned short* __restrict__ T2w){
  int k = blockIdx.y, tid = threadIdx.x, wave = tid >> 6, lane = tid & 63;
  __shared__ float Al[64*65];
  __shared__ float rds[64];
  for (int e = tid; e < 4096; e += 256) Al[(e>>6)*65 + (e&63)] = LmI[(size_t)k*4096 + e];
  if (tid < 64) rds[tid] = rdI[k*64 + tid];
  __syncthreads();
  int n = blockIdx.x*4 + wave;
  float x = Qf[((size_t)k*256 + n)*64 + lane];
  #pragma unroll
  for (int j = 0; j < 64; ++j){                 // forward: L z = q
    float zj = __shfl(x, j) * rds[j];
    x = (lane == j) ? zj : (lane > j ? x - Al[lane*65+j]*zj : x);
  }
  #pragma unroll
  for (int j = 63; j >= 0; --j){                // backward: L^T y = z
    float yj = __shfl(x, j) * rds[j];
    x = (lane == j) ? yj : (lane < j ? x - Al[j*65+lane]*yj : x);
  }
  float scale = 0.5f * wv[k];                   // ETA * w_k
  T2w[((size_t)k*256 + n)*64 + lane] = f2bf(scale * x);
}

// ---------------------------------------------------------------------------
// K7: hwT[d][m] = sum_k (-ETA*LAM_LAP*w_k) hops[k][m][d]  (bf16, transposed).
// ---------------------------------------------------------------------------
__global__ __launch_bounds__(256) void k_hwT(const float* __restrict__ hops,
                                             const float* __restrict__ wv,
                                             unsigned short* __restrict__ hwT){
  __shared__ float T[64*65];
  int n0 = blockIdx.x*64, d0 = blockIdx.y*64, tid = threadIdx.x;
  float wl[5];
  #pragma unroll
  for (int k = 0; k < 5; ++k) wl[k] = -0.15f * wv[k];   // -ETA*LAM_LAP*w_k
  for (int e = tid; e < 1024; e += 256){
    int row = e >> 4, c4 = (e & 15)*4;
    f32x4 acc = (f32x4){0,0,0,0};
    #pragma unroll
    for (int k = 0; k < 5; ++k){
      f32x4 v = *(const f32x4*)(hops + ((size_t)k*NNODE + n0 + row)*256 + d0 + c4);
      acc += v * wl[k];
    }
    T[row*65 + c4+0] = acc[0]; T[row*65 + c4+1] = acc[1];
    T[row*65 + c4+2] = acc[2]; T[row*65 + c4+3] = acc[3];
  }
  __syncthreads();
  for (int e = tid; e < 1024; e += 256){
    int dr = e >> 4, c4 = (e & 15)*4;
    unsigned short h0 = f2bf(T[(c4+0)*65 + dr]);
    unsigned short h1 = f2bf(T[(c4+1)*65 + dr]);
    unsigned short h2 = f2bf(T[(c4+2)*65 + dr]);
    unsigned short h3 = f2bf(T[(c4+3)*65 + dr]);
    uint2 u; u.x = (unsigned)h0 | ((unsigned)h1 << 16); u.y = (unsigned)h2 | ((unsigned)h3 << 16);
    *(uint2*)(hwT + (size_t)(d0+dr)*NNODE + n0 + c4) = u;
  }
}

// K8: W_in f32 -> bf16 (layout already B^T: [out][in])
__global__ void k_wbf(const float* __restrict__ W, unsigned short* __restrict__ Wbf){
  int e = (blockIdx.x*256 + threadIdx.x)*4;
  f32x4 v = *(const f32x4*)(W + e);
  uint2 u;
  u.x = (unsigned)f2bf(v[0]) | ((unsigned)f2bf(v[1]) << 16);
  u.y = (unsigned)f2bf(v[2]) | ((unsigned)f2bf(v[3]) << 16);
  *(uint2*)(Wbf + e) = u;
}

// ---------------------------------------------------------------------------
// K9: partial[y] = Lbf[:, yk:yk+1024] @ hwT^T  (bf16). grid(64,8).
// Pure-DMA m97 structure; chunk-padded LDS (1 KB chunks at 1040 B stride).
// Chunk layout: row d lives at chunk (d>>3), offset (d&7)*128 + col*2 bytes.
// Bank quad = (4*chunk + col/2) % 32 -> 8 lanes/quad on ds_read_b128 (balanced).
// ---------------------------------------------------------------------------
__global__ __launch_bounds__(256,2) void k_biggemm(const unsigned short* __restrict__ Lbf,
                                                   const unsigned short* __restrict__ Bt,
                                                   unsigned short* __restrict__ part){
  __shared__ __align__(16) unsigned short Al[16*520];   // 128 rows x 64, 16 chunks
  __shared__ __align__(16) unsigned short Bl[32*520];   // 256 rows x 64, 32 chunks
  int tid = threadIdx.x, lane = tid & 63, wave = tid >> 6;
  int q = lane >> 4, r = lane & 15;
  int m0 = blockIdx.x * 128;
  size_t kbase = (size_t)blockIdx.y * 1024;
  int sr = lane >> 3, sc8 = (lane & 7) * 8;   // DMA: within-chunk row / col(shorts)
  f32x4 acc[8][4];
  #pragma unroll
  for (int a = 0; a < 8; ++a)
    #pragma unroll
    for (int b = 0; b < 4; ++b) acc[a][b] = (f32x4){0,0,0,0};
  for (int it = 0; it < 16; ++it){
    size_t k0 = kbase + it*64;
    __syncthreads();
    #pragma unroll
    for (int i = 0; i < 12; ++i){             // 48 chunks: 16 A + 32 B
      int c = i*4 + wave;                     // wave-uniform
      if (c < 16){
        gl_lds16(Lbf + (size_t)(m0 + c*8 + sr)*NNODE + k0 + sc8,
                 (char*)Al + c*1040 + lane*16);
      } else {
        int cb = c - 16;
        gl_lds16(Bt + (size_t)(cb*8 + sr)*NNODE + k0 + sc8,
                 (char*)Bl + cb*1040 + lane*16);
      }
    }
    __syncthreads();
    #pragma unroll
    for (int h = 0; h < 2; ++h){
      int ko = h*32 + q*8;
      s16x8 b[4];
      #pragma unroll
      for (int ni = 0; ni < 4; ++ni){
        int d = wave*64 + ni*16 + r;
        b[ni] = *(const s16x8*)(Bl + (d>>3)*520 + (d&7)*64 + ko);
      }
      #pragma unroll
      for (int mi = 0; mi < 8; ++mi){
        int m = mi*16 + r;
        s16x8 a = *(const s16x8*)(Al + (m>>3)*520 + (m&7)*64 + ko);
        #pragma unroll
        for (int ni = 0; ni < 4; ++ni) acc[mi][ni] = mfma16(a, b[ni], acc[mi][ni]);
      }
    }
  }
  unsigned short* o = part + (size_t)blockIdx.y * 2097152;
  #pragma unroll
  for (int mi = 0; mi < 8; ++mi)
    #pragma unroll
    for (int ni = 0; ni < 4; ++ni)
      #pragma unroll
      for (int ii = 0; ii < 4; ++ii){
        int m = m0 + mi*16 + q*4 + ii;
        int n = wave*64 + ni*16 + r;
        o[(size_t)m*256 + n] = f2bf(acc[mi][ni][ii]);
      }
}

// ---------------------------------------------------------------------------
// K10: grad partial = Zstack[8192,320] @ T2w-stack[320,256] -> slab 8.
// ---------------------------------------------------------------------------
__global__ __launch_bounds__(256,2) void k_gradgemm(const unsigned short* __restrict__ Zt,
                                                    const unsigned short* __restrict__ T2w,
                                                    unsigned short* __restrict__ out){
  __shared__ __align__(16) unsigned short Al[32][64];
  __shared__ __align__(16) unsigned short Bl[256][64];
  int tid = threadIdx.x, lane = tid & 63, wave = tid >> 6;
  int q = lane >> 4, r = lane & 15;
  int m0 = blockIdx.x * 32;
  f32x4 acc[2][4];
  #pragma unroll
  for (int a = 0; a < 2; ++a)
    #pragma unroll
    for (int b = 0; b < 4; ++b) acc[a][b] = (f32x4){0,0,0,0};
  for (int kk = 0; kk < 5; ++kk){
    __syncthreads();
    {
      int o = wave*1024 + lane*16;
      gl_lds16((const char*)Zt + ((size_t)kk*NNODE + m0)*128 + o,
               (char*)&Al[0][0] + wave*1024);
    }
    #pragma unroll
    for (int i = 0; i < 8; ++i){
      int o = i*4096 + wave*1024 + lane*16;
      gl_lds16((const char*)T2w + (size_t)kk*32768 + o,
               (char*)&Bl[0][0] + i*4096 + wave*1024);
    }
    __syncthreads();
    #pragma unroll
    for (int h = 0; h < 2; ++h){
      int ko = h*32 + q*8;
      s16x8 b[4];
      #pragma unroll
      for (int ni = 0; ni < 4; ++ni) b[ni] = *(const s16x8*)&Bl[wave*64 + ni*16 + r][ko];
      #pragma unroll
      for (int mi = 0; mi < 2; ++mi){
        s16x8 a = *(const s16x8*)&Al[mi*16 + r][ko];
        #pragma unroll
        for (int ni = 0; ni < 4; ++ni) acc[mi][ni] = mfma16(a, b[ni], acc[mi][ni]);
      }
    }
  }
  #pragma unroll
  for (int mi = 0; mi < 2; ++mi)
    #pragma unroll
    for (int ni = 0; ni < 4; ++ni)
      #pragma unroll
      for (int ii = 0; ii < 4; ++ii){
        int m = m0 + mi*16 + q*4 + ii;
        int n = wave*64 + ni*16 + r;
        out[(size_t)m*256 + n] = f2bf(acc[mi][ni][ii]);
      }
}

// K11: H_half = H + sum(9 partial slabs); soft-threshold; -> Hprox bf16
__global__ __launch_bounds__(256) void k_combine(const float* __restrict__ H,
                                                 const unsigned short* __restrict__ part,
                                                 unsigned short* __restrict__ Hp){
  size_t e = ((size_t)blockIdx.x*256 + threadIdx.x)*4;
  f32x4 h = *(const f32x4*)(H + e);
  float s0 = h[0], s1 = h[1], s2 = h[2], s3 = h[3];
  #pragma unroll
  for (int sl = 0; sl < 9; ++sl){
    uint2 u = *(const uint2*)(part + (size_t)sl*2097152 + e);
    s0 += bf2f(u.x & 0xffff); s1 += bf2f(u.x >> 16);
    s2 += bf2f(u.y & 0xffff); s3 += bf2f(u.y >> 16);
  }
  #define PROX(a) ({ float _t = fabsf(a) - 0.025f; _t > 0.0f ? copysignf(_t,(a)) : 0.0f; })
  uint2 o;
  o.x = (unsigned)f2bf(PROX(s0)) | ((unsigned)f2bf(PROX(s1)) << 16);
  o.y = (unsigned)f2bf(PROX(s2)) | ((unsigned)f2bf(PROX(s3)) << 16);
  *(uint2*)(Hp + e) = o;
}

// K12: Hpre = Hprox @ W_in^T (bf16 MFMA). grid(128), BM=64 BN=256 K=256.
__global__ __launch_bounds__(256,2) void k_fingemm(const unsigned short* __restrict__ Hp,
                                                   const unsigned short* __restrict__ Wbf,
                                                   float* __restrict__ Hpre){
  __shared__ __align__(16) unsigned short Al[64][64];
  __shared__ __align__(16) unsigned short Bl[256][64];
  int tid = threadIdx.x, lane = tid & 63, wave = tid >> 6;
  int q = lane >> 4, r = lane & 15;
  int m0 = blockIdx.x * 64;
  f32x4 acc[4][4];
  #pragma unroll
  for (int a = 0; a < 4; ++a)
    #pragma unroll
    for (int b = 0; b < 4; ++b) acc[a][b] = (f32x4){0,0,0,0};
  for (int it = 0; it < 4; ++it){
    __syncthreads();
    #pragma unroll
    for (int i = 0; i < 2; ++i){
      int o = i*4096 + wave*1024 + lane*16;
      int row = o >> 7, kc = o & 127;
      gl_lds16((const char*)Hp + (size_t)(m0+row)*512 + it*128 + kc,
               (char*)&Al[0][0] + i*4096 + wave*1024);
    }
    #pragma unroll
    for (int i = 0; i < 8; ++i){
      int o = i*4096 + wave*1024 + lane*16;
      int n = o >> 7, kc = o & 127;
      gl_lds16((const char*)Wbf + (size_t)n*512 + it*128 + kc,
               (char*)&Bl[0][0] + i*4096 + wave*1024);
    }
    __syncthreads();
    #pragma unroll
    for (int h = 0; h < 2; ++h){
      int ko = h*32 + q*8;
      s16x8 b[4];
      #pragma unroll
      for (int ni = 0; ni < 4; ++ni) b[ni] = *(const s16x8*)&Bl[wave*64 + ni*16 + r][ko];
      #pragma unroll
      for (int mi = 0; mi < 4; ++mi){
        s16x8 a = *(const s16x8*)&Al[mi*16 + r][ko];
        #pragma unroll
        for (int ni = 0; ni < 4; ++ni) acc[mi][ni] = mfma16(a, b[ni], acc[mi][ni]);
      }
    }
  }
  #pragma unroll
  for (int mi = 0; mi < 4; ++mi)
    #pragma unroll
    for (int ni = 0; ni < 4; ++ni)
      #pragma unroll
      for (int ii = 0; ii < 4; ++ii){
        int m = m0 + mi*16 + q*4 + ii;
        int n = wave*64 + ni*16 + r;
        Hpre[(size_t)m*256 + n] = acc[mi][ni][ii];
      }
}

// K13: LayerNorm per row (256). 1 wave per row, 4 rows/block.
__global__ __launch_bounds__(256) void k_ln(const float* __restrict__ Hpre,
                                            const float* __restrict__ gamma,
                                            const float* __restrict__ beta,
                                            float* __restrict__ out){
  int row = blockIdx.x*4 + (threadIdx.x >> 6);
  int lane = threadIdx.x & 63;
  f32x4 x = *(const f32x4*)(Hpre + (size_t)row*256 + lane*4);
  float sm = x[0]+x[1]+x[2]+x[3];
  float sq = x[0]*x[0]+x[1]*x[1]+x[2]*x[2]+x[3]*x[3];
  #pragma unroll
  for (int o = 1; o < 64; o <<= 1){ sm += __shfl_xor(sm, o, 64); sq += __shfl_xor(sq, o, 64); }
  float mean = sm * (1.0f/256.0f);
  float var  = sq * (1.0f/256.0f) - mean*mean;
  float rs   = rsqrtf(var + 1e-5f);
  f32x4 g = *(const f32x4*)(gamma + lane*4);
  f32x4 b = *(const f32x4*)(beta  + lane*4);
  f32x4 y;
  #pragma unroll
  for (int i = 0; i < 4; ++i) y[i] = (x[i]-mean)*rs*g[i] + b[i];
  *(f32x4*)(out + (size_t)row*256 + lane*4) = y;
}

// ===========================================================================
extern "C" void kernel_launch(void* const* d_in, const int* in_sizes, int n_in,
                              void* d_out, int out_size, void* d_ws, size_t ws_size,
                              hipStream_t stream){
  const float* H    = (const float*)d_in[0];
  const float* hops = (const float*)d_in[1];
  const float* Lmat = (const float*)d_in[2];
  const float* U    = (const float*)d_in[3];
  const float* Win  = (const float*)d_in[4];
  const float* gam  = (const float*)d_in[5];
  const float* bet  = (const float*)d_in[6];
  const float* ltau = (const float*)d_in[7];
  float* out = (float*)d_out;

  char* ws = (char*)d_ws;
  float*          Qf   = (float*)(ws + OFF_Q);
  unsigned short* Qt   = (unsigned short*)(ws + OFF_QT);
  unsigned short* Zt   = (unsigned short*)(ws + OFF_ZT);
  float*          Gp   = (float*)(ws + OFF_GP);
  float*          Lm   = (float*)(ws + OFF_LM);
  float*          rdw  = (float*)(ws + OFF_RD);
  float*          Lu   = (float*)(ws + OFF_LU);
  float*          rdu  = (float*)(ws + OFF_RDU);
  float*          re   = (float*)(ws + OFF_RE);
  float*          wv   = (float*)(ws + OFF_W);
  unsigned short* T2w  = (unsigned short*)(ws + OFF_T2);
  unsigned short* hwT  = (unsigned short*)(ws + OFF_HWT);
  unsigned short* Wbf  = (unsigned short*)(ws + OFF_WBF);
  unsigned short* Hp   = (unsigned short*)(ws + OFF_HP);
  unsigned short* part = (unsigned short*)(ws + OFF_PART);
  float*          Hpre = (float*)(ws + OFF_HPRE);
  unsigned short* Lbf  = (unsigned short*)(ws + OFF_LBF);

  hipLaunchKernelGGL(k_lbf,     dim3(32768),    dim3(256), 0, stream, Lmat, Lbf);
  hipLaunchKernelGGL(k_gramchol,dim3(5),        dim3(256), 0, stream, U, Lu, rdu);
  hipLaunchKernelGGL(k_qsolve,  dim3(64,5),     dim3(256), 0, stream, U, Lu, rdu, Qf, Qt);
  hipLaunchKernelGGL(k_zgemm,   dim3(64,5),     dim3(256), 0, stream, hops, Qt, Zt);
  hipLaunchKernelGGL(k_gpart,   dim3(5,16),     dim3(256), 0, stream, Zt, Gp);
  hipLaunchKernelGGL(k_gred,    dim3(5),        dim3(256), 0, stream, Gp, Lm, rdw, re);
  hipLaunchKernelGGL(k_soft,    dim3(1),        dim3(64),  0, stream, re, ltau, wv, out + 2097152);
  hipLaunchKernelGGL(k_t2w,     dim3(64,5),     dim3(256), 0, stream, Qf, Lm, rdw, wv, T2w);
  hipLaunchKernelGGL(k_hwT,     dim3(128,4),    dim3(256), 0, stream, hops, wv, hwT);
  hipLaunchKernelGGL(k_wbf,     dim3(64),       dim3(256), 0, stream, Win, Wbf);
  hipLaunchKernelGGL(k_biggemm, dim3(64,8),     dim3(256), 0, stream, Lbf, hwT, part);
  hipLaunchKernelGGL(k_gradgemm,dim3(256),      dim3(256), 0, stream, Zt, T2w, part + (size_t)8*2097152);
  hipLaunchKernelGGL(k_combine, dim3(2048),     dim3(256), 0, stream, H, part, Hp);
  hipLaunchKernelGGL(k_fingemm, dim3(128),      dim3(256), 0, stream, Hp, Wbf, Hpre);
  hipLaunchKernelGGL(k_ln,      dim3(2048),     dim3(256), 0, stream, Hpre, gam, bet, out);
}